// Round 1
// baseline (272.509 us; speedup 1.0000x reference)
//
#include <hip/hip_runtime.h>
#include <hip/hip_bf16.h>
#include <cstdint>
#include <cstddef>

// Problem dims (fixed)
#define B_   4
#define N_   1024
#define C_   768
#define H_   12
#define D_   64
#define HID_ 3072
#define M_   4096  // B*N
static constexpr float ATT_SCALE = 0.125f;  // D^-0.5

typedef __attribute__((ext_vector_type(8))) short short8;
typedef __attribute__((ext_vector_type(8))) unsigned short ushort8;
typedef __attribute__((ext_vector_type(4))) float f32x4;

__device__ __forceinline__ void gload16(const void* g, void* l) {
  __builtin_amdgcn_global_load_lds(
      (const __attribute__((address_space(1))) void*)g,
      (__attribute__((address_space(3))) void*)l, 16, 0, 0);
}

__device__ __forceinline__ unsigned short f2bf(float f) {
  __hip_bfloat16 h = __float2bfloat16(f);
  return __builtin_bit_cast(unsigned short, h);
}

// ---------------- weight fp32 -> bf16 transpose ----------------
// W [K][Nn] fp32 row-major  ->  Wt [Nn][K] bf16 row-major
__global__ __launch_bounds__(256) void wconv(const float* __restrict__ W,
                                             unsigned short* __restrict__ Wt,
                                             int K, int Nn) {
  __shared__ float tile[32][33];
  const int tx = threadIdx.x & 31, ty = threadIdx.x >> 5;  // 32 x 8
  const int n0 = blockIdx.x * 32, k0 = blockIdx.y * 32;
#pragma unroll
  for (int i = 0; i < 32; i += 8)
    tile[ty + i][tx] = W[(size_t)(k0 + ty + i) * Nn + n0 + tx];
  __syncthreads();
#pragma unroll
  for (int i = 0; i < 32; i += 8)
    Wt[(size_t)(n0 + ty + i) * K + k0 + tx] = f2bf(tile[tx][ty + i]);
}

// ---------------- LayerNorm (fp32 in -> bf16 out) ----------------
__global__ __launch_bounds__(256) void ln_kernel(const float* __restrict__ x,
                                                 const float* __restrict__ w,
                                                 const float* __restrict__ b,
                                                 unsigned short* __restrict__ out) {
  __shared__ float sbuf[8];
  const int row = blockIdx.x;
  const int t = threadIdx.x;
  const float* xr = x + (size_t)row * C_;
  float v0 = xr[t], v1 = xr[t + 256], v2 = xr[t + 512];
  float s = v0 + v1 + v2;
  float ss = v0 * v0 + v1 * v1 + v2 * v2;
#pragma unroll
  for (int m = 32; m >= 1; m >>= 1) {
    s += __shfl_xor(s, m);
    ss += __shfl_xor(ss, m);
  }
  const int wave = t >> 6, lane = t & 63;
  if (lane == 0) { sbuf[wave] = s; sbuf[4 + wave] = ss; }
  __syncthreads();
  s = sbuf[0] + sbuf[1] + sbuf[2] + sbuf[3];
  ss = sbuf[4] + sbuf[5] + sbuf[6] + sbuf[7];
  const float mu = s * (1.f / C_);
  const float var = ss * (1.f / C_) - mu * mu;
  const float rstd = rsqrtf(var + 1e-6f);
  unsigned short* o = out + (size_t)row * C_;
  o[t]       = f2bf((v0 - mu) * rstd * w[t]       + b[t]);
  o[t + 256] = f2bf((v1 - mu) * rstd * w[t + 256] + b[t + 256]);
  o[t + 512] = f2bf((v2 - mu) * rstd * w[t + 512] + b[t + 512]);
}

// ---------------- GEMM: C = A[M,K] * Bt[N,K]^T + bias, fused epilogue ----------
// A bf16 row-major, Bt bf16 row-major (i.e. B^T). 128x128 tile, BK=32, 4 waves.
template <bool GELU, bool RES, bool OUTF, bool OUTB>
__global__ __launch_bounds__(256) void gemm_bt(const unsigned short* __restrict__ A,
                                               const unsigned short* __restrict__ Bt,
                                               const float* __restrict__ bias,
                                               const float* __restrict__ res,
                                               float* __restrict__ outF,
                                               unsigned short* __restrict__ outB,
                                               int M, int Nn, int K) {
  __shared__ unsigned short As[128 * 32];
  __shared__ unsigned short Bs[128 * 32];
  const int t = threadIdx.x;
  const int lane = t & 63;
  const int wave = t >> 6;
  const int wm = wave >> 1, wn = wave & 1;
  const int bm = blockIdx.x, bn = blockIdx.y;
  const int r15 = lane & 15, g = lane >> 4;

  f32x4 acc[4][4];
#pragma unroll
  for (int m = 0; m < 4; ++m)
#pragma unroll
    for (int n = 0; n < 4; ++n) acc[m][n] = (f32x4){0.f, 0.f, 0.f, 0.f};

  const unsigned short* ga = A + (size_t)(bm * 128 + (t >> 2)) * K + (t & 3) * 8;
  const unsigned short* gb = Bt + (size_t)(bn * 128 + (t >> 2)) * K + (t & 3) * 8;
  char* lA = (char*)As + wave * 1024;
  char* lB = (char*)Bs + wave * 1024;

  const int nk = K >> 5;
  for (int kt = 0; kt < nk; ++kt) {
    __syncthreads();
    gload16(ga, lA);
    gload16(ga + (size_t)64 * K, lA + 4096);
    gload16(gb, lB);
    gload16(gb + (size_t)64 * K, lB + 4096);
    ga += 32;
    gb += 32;
    __syncthreads();
    short8 af[4], bf[4];
#pragma unroll
    for (int m = 0; m < 4; ++m)
      af[m] = *(const short8*)(As + (wm * 64 + m * 16 + r15) * 32 + g * 8);
#pragma unroll
    for (int n = 0; n < 4; ++n)
      bf[n] = *(const short8*)(Bs + (wn * 64 + n * 16 + r15) * 32 + g * 8);
#pragma unroll
    for (int m = 0; m < 4; ++m)
#pragma unroll
      for (int n = 0; n < 4; ++n)
        acc[m][n] = __builtin_amdgcn_mfma_f32_16x16x32_bf16(af[m], bf[n], acc[m][n], 0, 0, 0);
  }

#pragma unroll
  for (int m = 0; m < 4; ++m) {
#pragma unroll
    for (int n = 0; n < 4; ++n) {
#pragma unroll
      for (int r = 0; r < 4; ++r) {
        const int row = bm * 128 + wm * 64 + m * 16 + g * 4 + r;
        const int col = bn * 128 + wn * 64 + n * 16 + r15;
        float v = acc[m][n][r] + bias[col];
        if (GELU) v = 0.5f * v * (1.f + erff(v * 0.70710678118654752f));
        if (RES) v += res[(size_t)row * Nn + col];
        if (OUTF) outF[(size_t)row * Nn + col] = v;
        if (OUTB) outB[(size_t)row * Nn + col] = f2bf(v);
      }
    }
  }
}

// ---------------- fused biased attention ----------------
// qkv: [M_, 3*C_] bf16 ([B,N][s,h,d]); pbias: [B,N,N] fp32; o: [M_, C_] bf16
// grid: (N/64, B*H); block: 256 (4 waves x 16 q-rows)
__global__ __launch_bounds__(256) void attn_kernel(const unsigned short* __restrict__ qkv,
                                                   const float* __restrict__ pbias,
                                                   unsigned short* __restrict__ o) {
  __shared__ unsigned short Ks[64 * 64];
  __shared__ unsigned short Vt[64 * 64];
  __shared__ unsigned short Ps[4][16 * 64];
  const int t = threadIdx.x, lane = t & 63, wave = t >> 6;
  const int bh = blockIdx.y;
  const int b = bh / H_, h = bh % H_;
  const int q0 = blockIdx.x * 64;
  const int r15 = lane & 15, g = lane >> 4;
  const int qrow = q0 + wave * 16;

  // Q fragments (A-operand), held for the whole kernel
  short8 aq[2];
  const unsigned short* qp =
      qkv + (size_t)(b * N_ + qrow + r15) * (3 * C_) + h * D_ + g * 8;
  aq[0] = *(const short8*)qp;
  aq[1] = *(const short8*)(qp + 32);

  f32x4 oacc[4];
#pragma unroll
  for (int n = 0; n < 4; ++n) oacc[n] = (f32x4){0.f, 0.f, 0.f, 0.f};
  float m_run[4], l_run[4];
#pragma unroll
  for (int r = 0; r < 4; ++r) { m_run[r] = -1e30f; l_run[r] = 0.f; }

  const unsigned short* kbase = qkv + (size_t)b * N_ * (3 * C_) + C_ + h * D_;
  const unsigned short* vbase = qkv + (size_t)b * N_ * (3 * C_) + 2 * C_ + h * D_;
  const float* bb = pbias + (size_t)b * N_ * N_;

  for (int kb = 0; kb < N_ / 64; ++kb) {
    __syncthreads();
    // stage K block [64 keys][64 d] via global_load_lds (linear)
    const unsigned short* kg = kbase + (size_t)(kb * 64 + (t >> 3)) * (3 * C_) + (t & 7) * 8;
    gload16(kg, (char*)Ks + wave * 1024);
    gload16(kg + (size_t)32 * (3 * C_), (char*)Ks + wave * 1024 + 4096);
    // stage V transposed: Vt[d][key]
    {
      const int key = t >> 3, d0 = (t & 7) * 8;
      const ushort8 v0 =
          *(const ushort8*)(vbase + (size_t)(kb * 64 + key) * (3 * C_) + d0);
      const ushort8 v1 =
          *(const ushort8*)(vbase + (size_t)(kb * 64 + 32 + key) * (3 * C_) + d0);
#pragma unroll
      for (int j = 0; j < 8; ++j) {
        Vt[(d0 + j) * 64 + key] = v0[j];
        Vt[(d0 + j) * 64 + key + 32] = v1[j];
      }
    }
    __syncthreads();

    // S = Q K^T (16 x 64 per wave)
    f32x4 sacc[4];
#pragma unroll
    for (int n = 0; n < 4; ++n) sacc[n] = (f32x4){0.f, 0.f, 0.f, 0.f};
#pragma unroll
    for (int kk = 0; kk < 2; ++kk) {
#pragma unroll
      for (int n = 0; n < 4; ++n) {
        short8 bk = *(const short8*)(Ks + (n * 16 + r15) * 64 + kk * 32 + g * 8);
        sacc[n] = __builtin_amdgcn_mfma_f32_16x16x32_bf16(aq[kk], bk, sacc[n], 0, 0, 0);
      }
    }

    // scale + physics bias, online softmax
    float p[4][4];   // [n][r]
    float mb[4];
#pragma unroll
    for (int r = 0; r < 4; ++r) mb[r] = -1e30f;
#pragma unroll
    for (int n = 0; n < 4; ++n) {
#pragma unroll
      for (int r = 0; r < 4; ++r) {
        const int row = g * 4 + r;
        float s = sacc[n][r] * ATT_SCALE +
                  bb[(size_t)(qrow + row) * N_ + kb * 64 + n * 16 + r15];
        p[n][r] = s;
        mb[r] = fmaxf(mb[r], s);
      }
    }
#pragma unroll
    for (int r = 0; r < 4; ++r) {
      mb[r] = fmaxf(mb[r], __shfl_xor(mb[r], 1));
      mb[r] = fmaxf(mb[r], __shfl_xor(mb[r], 2));
      mb[r] = fmaxf(mb[r], __shfl_xor(mb[r], 4));
      mb[r] = fmaxf(mb[r], __shfl_xor(mb[r], 8));
      const float mn = fmaxf(m_run[r], mb[r]);
      const float corr = expf(m_run[r] - mn);
      m_run[r] = mn;
      float rs = 0.f;
#pragma unroll
      for (int n = 0; n < 4; ++n) {
        p[n][r] = expf(p[n][r] - mn);
        rs += p[n][r];
      }
      rs += __shfl_xor(rs, 1);
      rs += __shfl_xor(rs, 2);
      rs += __shfl_xor(rs, 4);
      rs += __shfl_xor(rs, 8);
      l_run[r] = l_run[r] * corr + rs;
#pragma unroll
      for (int n = 0; n < 4; ++n) oacc[n][r] *= corr;
    }

    // write P (bf16) to per-wave LDS
#pragma unroll
    for (int n = 0; n < 4; ++n)
#pragma unroll
      for (int r = 0; r < 4; ++r)
        Ps[wave][(g * 4 + r) * 64 + n * 16 + r15] = f2bf(p[n][r]);
    __syncthreads();

    // O += P V
#pragma unroll
    for (int kk = 0; kk < 2; ++kk) {
      short8 ap = *(const short8*)(&Ps[wave][r15 * 64 + kk * 32 + g * 8]);
#pragma unroll
      for (int n = 0; n < 4; ++n) {
        short8 bv = *(const short8*)(Vt + (n * 16 + r15) * 64 + kk * 32 + g * 8);
        oacc[n] = __builtin_amdgcn_mfma_f32_16x16x32_bf16(ap, bv, oacc[n], 0, 0, 0);
      }
    }
  }

  // normalize and store o (bf16)
#pragma unroll
  for (int n = 0; n < 4; ++n) {
#pragma unroll
    for (int r = 0; r < 4; ++r) {
      const int row = qrow + g * 4 + r;
      const float v = oacc[n][r] / l_run[r];
      o[(size_t)(b * N_ + row) * C_ + h * D_ + n * 16 + r15] = f2bf(v);
    }
  }
}

// ---------------- launcher ----------------
extern "C" void kernel_launch(void* const* d_in, const int* in_sizes, int n_in,
                              void* d_out, int out_size, void* d_ws, size_t ws_size,
                              hipStream_t stream) {
  const float* x      = (const float*)d_in[0];
  const float* pbias  = (const float*)d_in[1];
  const float* qkv_w  = (const float*)d_in[2];
  const float* qkv_b  = (const float*)d_in[3];
  const float* proj_w = (const float*)d_in[4];
  const float* proj_b = (const float*)d_in[5];
  const float* n1_w   = (const float*)d_in[6];
  const float* n1_b   = (const float*)d_in[7];
  const float* n2_w   = (const float*)d_in[8];
  const float* n2_b   = (const float*)d_in[9];
  const float* fc1_w  = (const float*)d_in[10];
  const float* fc1_b  = (const float*)d_in[11];
  const float* fc2_w  = (const float*)d_in[12];
  const float* fc2_b  = (const float*)d_in[13];
  float* out = (float*)d_out;

  char* ws = (char*)d_ws;
  // bf16 transposed weights
  unsigned short* wt_qkv  = (unsigned short*)(ws + 0);          // 2304x768
  unsigned short* wt_proj = (unsigned short*)(ws + 3538944);    // 768x768
  unsigned short* wt_fc1  = (unsigned short*)(ws + 4718592);    // 3072x768
  unsigned short* wt_fc2  = (unsigned short*)(ws + 9437184);    // 768x3072
  float*          x2      = (float*)(ws + 14155776);            // 4096x768 fp32
  unsigned short* h1      = (unsigned short*)(ws + 26738688);   // 4096x768 bf16 (h1 / o / h2)
  unsigned short* qkvb    = (unsigned short*)(ws + 33030144);   // 4096x2304 bf16 (qkv / h3)

  // weights -> bf16 transposed
  wconv<<<dim3(2304 / 32, 768 / 32), 256, 0, stream>>>(qkv_w, wt_qkv, 768, 2304);
  wconv<<<dim3(768 / 32, 768 / 32), 256, 0, stream>>>(proj_w, wt_proj, 768, 768);
  wconv<<<dim3(3072 / 32, 768 / 32), 256, 0, stream>>>(fc1_w, wt_fc1, 768, 3072);
  wconv<<<dim3(768 / 32, 3072 / 32), 256, 0, stream>>>(fc2_w, wt_fc2, 3072, 768);

  // h1 = LN1(x)
  ln_kernel<<<M_, 256, 0, stream>>>(x, n1_w, n1_b, h1);
  // qkv = h1 @ qkv_w + qkv_b
  gemm_bt<false, false, false, true><<<dim3(32, 18), 256, 0, stream>>>(
      h1, wt_qkv, qkv_b, nullptr, nullptr, qkvb, M_, 3 * C_, C_);
  // o = attention(qkv, pbias)   (writes into h1 region)
  attn_kernel<<<dim3(N_ / 64, B_ * H_), 256, 0, stream>>>(qkvb, pbias, h1);
  // x2 = x + o @ proj_w + proj_b
  gemm_bt<false, true, true, false><<<dim3(32, 6), 256, 0, stream>>>(
      h1, wt_proj, proj_b, x, x2, nullptr, M_, C_, C_);
  // h2 = LN2(x2)  (reuse h1 region)
  ln_kernel<<<M_, 256, 0, stream>>>(x2, n2_w, n2_b, h1);
  // h3 = gelu(h2 @ fc1_w + fc1_b)  (reuse qkv region)
  gemm_bt<true, false, false, true><<<dim3(32, 24), 256, 0, stream>>>(
      h1, wt_fc1, fc1_b, nullptr, nullptr, qkvb, M_, HID_, C_);
  // out = x2 + h3 @ fc2_w + fc2_b
  gemm_bt<false, true, true, false><<<dim3(32, 6), 256, 0, stream>>>(
      qkvb, wt_fc2, fc2_b, x2, out, nullptr, M_, C_, HID_);
}

// Round 2
// 236.896 us; speedup vs baseline: 1.1503x; 1.1503x over previous
//
#include <hip/hip_runtime.h>
#include <hip/hip_bf16.h>
#include <cstdint>
#include <cstddef>

// Problem dims (fixed)
#define B_   4
#define N_   1024
#define C_   768
#define H_   12
#define D_   64
#define HID_ 3072
#define M_   4096  // B*N

typedef __attribute__((ext_vector_type(8))) short short8;
typedef __attribute__((ext_vector_type(8))) unsigned short ushort8;
typedef __attribute__((ext_vector_type(4))) float f32x4;

__device__ __forceinline__ void gload16(const void* g, void* l) {
  __builtin_amdgcn_global_load_lds(
      (const __attribute__((address_space(1))) void*)g,
      (__attribute__((address_space(3))) void*)l, 16, 0, 0);
}

__device__ __forceinline__ unsigned short f2bf(float f) {
  __hip_bfloat16 h = __float2bfloat16(f);
  return __builtin_bit_cast(unsigned short, h);
}
__device__ __forceinline__ float bf2f(unsigned short u) {
  unsigned int x = ((unsigned int)u) << 16;
  return __builtin_bit_cast(float, x);
}
__device__ __forceinline__ float ex2(float x) {
  float r;
  asm("v_exp_f32 %0, %1" : "=v"(r) : "v"(x));
  return r;
}

// ---------------- weight fp32 -> bf16 transpose ----------------
__global__ __launch_bounds__(256) void wconv(const float* __restrict__ W,
                                             unsigned short* __restrict__ Wt,
                                             int K, int Nn) {
  __shared__ float tile[32][33];
  const int tx = threadIdx.x & 31, ty = threadIdx.x >> 5;  // 32 x 8
  const int n0 = blockIdx.x * 32, k0 = blockIdx.y * 32;
#pragma unroll
  for (int i = 0; i < 32; i += 8)
    tile[ty + i][tx] = W[(size_t)(k0 + ty + i) * Nn + n0 + tx];
  __syncthreads();
#pragma unroll
  for (int i = 0; i < 32; i += 8)
    Wt[(size_t)(n0 + ty + i) * K + k0 + tx] = f2bf(tile[tx][ty + i]);
}

// ---------------- LayerNorm (fp32 in -> bf16 out) ----------------
__global__ __launch_bounds__(256) void ln_kernel(const float* __restrict__ x,
                                                 const float* __restrict__ w,
                                                 const float* __restrict__ b,
                                                 unsigned short* __restrict__ out) {
  __shared__ float sbuf[8];
  const int row = blockIdx.x;
  const int t = threadIdx.x;
  const float* xr = x + (size_t)row * C_;
  float v0 = xr[t], v1 = xr[t + 256], v2 = xr[t + 512];
  float s = v0 + v1 + v2;
  float ss = v0 * v0 + v1 * v1 + v2 * v2;
#pragma unroll
  for (int m = 32; m >= 1; m >>= 1) {
    s += __shfl_xor(s, m);
    ss += __shfl_xor(ss, m);
  }
  const int wave = t >> 6, lane = t & 63;
  if (lane == 0) { sbuf[wave] = s; sbuf[4 + wave] = ss; }
  __syncthreads();
  s = sbuf[0] + sbuf[1] + sbuf[2] + sbuf[3];
  ss = sbuf[4] + sbuf[5] + sbuf[6] + sbuf[7];
  const float mu = s * (1.f / C_);
  const float var = ss * (1.f / C_) - mu * mu;
  const float rstd = rsqrtf(var + 1e-6f);
  unsigned short* o = out + (size_t)row * C_;
  o[t]       = f2bf((v0 - mu) * rstd * w[t]       + b[t]);
  o[t + 256] = f2bf((v1 - mu) * rstd * w[t + 256] + b[t + 256]);
  o[t + 512] = f2bf((v2 - mu) * rstd * w[t + 512] + b[t + 512]);
}

// ---------------- GEMM: C = A[M,K] * Bt[N,K]^T + bias, fused epilogue ----------
template <bool GELU, bool RES, bool OUTF, bool OUTB>
__global__ __launch_bounds__(256) void gemm_bt(const unsigned short* __restrict__ A,
                                               const unsigned short* __restrict__ Bt,
                                               const float* __restrict__ bias,
                                               const float* __restrict__ res,
                                               float* __restrict__ outF,
                                               unsigned short* __restrict__ outB,
                                               int M, int Nn, int K) {
  __shared__ unsigned short As[128 * 32];
  __shared__ unsigned short Bs[128 * 32];
  const int t = threadIdx.x;
  const int lane = t & 63;
  const int wave = t >> 6;
  const int wm = wave >> 1, wn = wave & 1;
  const int bm = blockIdx.x, bn = blockIdx.y;
  const int r15 = lane & 15, g = lane >> 4;

  f32x4 acc[4][4];
#pragma unroll
  for (int m = 0; m < 4; ++m)
#pragma unroll
    for (int n = 0; n < 4; ++n) acc[m][n] = (f32x4){0.f, 0.f, 0.f, 0.f};

  const unsigned short* ga = A + (size_t)(bm * 128 + (t >> 2)) * K + (t & 3) * 8;
  const unsigned short* gb = Bt + (size_t)(bn * 128 + (t >> 2)) * K + (t & 3) * 8;
  char* lA = (char*)As + wave * 1024;
  char* lB = (char*)Bs + wave * 1024;

  const int nk = K >> 5;
  for (int kt = 0; kt < nk; ++kt) {
    __syncthreads();
    gload16(ga, lA);
    gload16(ga + (size_t)64 * K, lA + 4096);
    gload16(gb, lB);
    gload16(gb + (size_t)64 * K, lB + 4096);
    ga += 32;
    gb += 32;
    __syncthreads();
    short8 af[4], bf[4];
#pragma unroll
    for (int m = 0; m < 4; ++m)
      af[m] = *(const short8*)(As + (wm * 64 + m * 16 + r15) * 32 + g * 8);
#pragma unroll
    for (int n = 0; n < 4; ++n)
      bf[n] = *(const short8*)(Bs + (wn * 64 + n * 16 + r15) * 32 + g * 8);
#pragma unroll
    for (int m = 0; m < 4; ++m)
#pragma unroll
      for (int n = 0; n < 4; ++n)
        acc[m][n] = __builtin_amdgcn_mfma_f32_16x16x32_bf16(af[m], bf[n], acc[m][n], 0, 0, 0);
  }

#pragma unroll
  for (int m = 0; m < 4; ++m) {
#pragma unroll
    for (int n = 0; n < 4; ++n) {
#pragma unroll
      for (int r = 0; r < 4; ++r) {
        const int row = bm * 128 + wm * 64 + m * 16 + g * 4 + r;
        const int col = bn * 128 + wn * 64 + n * 16 + r15;
        float v = acc[m][n][r] + bias[col];
        if (GELU) v = 0.5f * v * (1.f + erff(v * 0.70710678118654752f));
        if (RES) v += res[(size_t)row * Nn + col];
        if (OUTF) outF[(size_t)row * Nn + col] = v;
        if (OUTB) outB[(size_t)row * Nn + col] = f2bf(v);
      }
    }
  }
}

// ---------------- fused biased attention (swizzled LDS, double-buffered) -------
// qkv: [M_, 3*C_] bf16; pbias: [B,N,N] fp32; o: [M_, C_] bf16
// grid: (N/64, B*H); block: 256 (4 waves x 16 q-rows)
// All LDS tiles are [rows][64] bf16 (128B rows) with XOR swizzle:
//   byte(row, chunk16) = row*128 + ((chunk ^ (row&7))<<4)
__global__ __launch_bounds__(256) void attn_kernel(const unsigned short* __restrict__ qkv,
                                                   const float* __restrict__ pbias,
                                                   unsigned short* __restrict__ o) {
  __shared__ unsigned short Ks[2][64 * 64];
  __shared__ unsigned short Vt[2][64 * 64];
  __shared__ unsigned short Ps[4][16 * 64];
  const int t = threadIdx.x, lane = t & 63, wave = t >> 6;
  const int bh = blockIdx.y;
  const int b = bh / H_, h = bh % H_;
  const int q0 = blockIdx.x * 64;
  const int r15 = lane & 15, g = lane >> 4;
  const int qrow = q0 + wave * 16;
  const float LOG2E = 1.44269504088896f;
  const float QS = 0.125f * 1.44269504088896f;  // SCALE * log2(e)

  // Q fragments, pre-scaled by SCALE*log2e (softmax runs in log2 domain)
  short8 aq[2];
  {
    const unsigned short* qp =
        qkv + (size_t)(b * N_ + qrow + r15) * (3 * C_) + h * D_ + g * 8;
    const ushort8 r0 = *(const ushort8*)qp;
    const ushort8 r1 = *(const ushort8*)(qp + 32);
#pragma unroll
    for (int j = 0; j < 8; ++j) {
      aq[0][j] = (short)f2bf(bf2f(r0[j]) * QS);
      aq[1][j] = (short)f2bf(bf2f(r1[j]) * QS);
    }
  }

  f32x4 oacc[4];
#pragma unroll
  for (int n = 0; n < 4; ++n) oacc[n] = (f32x4){0.f, 0.f, 0.f, 0.f};
  float m_run[4], l_run[4];
#pragma unroll
  for (int r = 0; r < 4; ++r) { m_run[r] = -1e30f; l_run[r] = 0.f; }

  const unsigned short* kbase = qkv + (size_t)b * N_ * (3 * C_) + C_ + h * D_;
  const unsigned short* vbase = qkv + (size_t)b * N_ * (3 * C_) + 2 * C_ + h * D_;
  const float* bb = pbias + (size_t)b * N_ * N_;

  // K staging source (pre-swizzled chunk so linear gload_lds dest = swizzled layout)
  const int krow = t >> 3;                          // 0..31
  const int kchunk = (t & 7) ^ (krow & 7);          // swizzled d-chunk
  // V staging assignment: thread -> (key pair, d group); conflict-free swizzled writes
  const int vp = t & 31;        // key pair: keys 2vp, 2vp+1
  const int vq = t >> 5;        // d group: d = vq*8 .. vq*8+7
  const int vkey = vp * 2, vd0 = vq * 8;

#define STAGE(kb_, nb_)                                                              \
  {                                                                                  \
    const unsigned short* kg =                                                       \
        kbase + (size_t)((kb_)*64 + krow) * (3 * C_) + kchunk * 8;                   \
    gload16(kg, (char*)Ks[nb_] + wave * 1024);                                       \
    gload16(kg + (size_t)32 * (3 * C_), (char*)Ks[nb_] + wave * 1024 + 4096);        \
    const unsigned short* vg = vbase + (size_t)((kb_)*64 + vkey) * (3 * C_) + vd0;   \
    const ushort8 va = *(const ushort8*)vg;                                          \
    const ushort8 vb2 = *(const ushort8*)(vg + 3 * C_);                              \
    char* vdst = (char*)Vt[nb_];                                                     \
    _Pragma("unroll") for (int j = 0; j < 8; ++j) {                                  \
      const int d = vd0 + j;                                                         \
      const unsigned int pack = (unsigned int)va[j] | ((unsigned int)vb2[j] << 16);  \
      *(unsigned int*)(vdst + d * 128 + (((vp >> 2) ^ (d & 7)) << 4) +               \
                       (vp & 3) * 4) = pack;                                         \
    }                                                                                \
  }

  STAGE(0, 0);

  for (int kb = 0; kb < N_ / 64; ++kb) {
    const int cur = kb & 1;
    __syncthreads();  // staging of kb visible; prior reads of other buffer done
    if (kb + 1 < N_ / 64) STAGE(kb + 1, cur ^ 1);

    // bias loads (issued before MFMA so latency overlaps)
    float bvv[4][4];
#pragma unroll
    for (int n = 0; n < 4; ++n)
#pragma unroll
      for (int r = 0; r < 4; ++r)
        bvv[n][r] = bb[(size_t)(qrow + g * 4 + r) * N_ + kb * 64 + n * 16 + r15];

    // S = Q K^T (16 x 64 per wave), log2-scaled domain
    const unsigned short* Ksc = Ks[cur];
    f32x4 sacc[4];
#pragma unroll
    for (int n = 0; n < 4; ++n) sacc[n] = (f32x4){0.f, 0.f, 0.f, 0.f};
#pragma unroll
    for (int kk = 0; kk < 2; ++kk) {
#pragma unroll
      for (int n = 0; n < 4; ++n) {
        short8 bk = *(const short8*)(Ksc + (n * 16 + r15) * 64 +
                                     (((kk * 4 + g) ^ (r15 & 7)) << 3));
        sacc[n] = __builtin_amdgcn_mfma_f32_16x16x32_bf16(aq[kk], bk, sacc[n], 0, 0, 0);
      }
    }

    // online softmax (log2 domain, defer-max)
    float p[4][4], tm[4];
#pragma unroll
    for (int r = 0; r < 4; ++r) tm[r] = -3e38f;
#pragma unroll
    for (int n = 0; n < 4; ++n)
#pragma unroll
      for (int r = 0; r < 4; ++r) {
        const float s = fmaf(bvv[n][r], LOG2E, sacc[n][r]);
        p[n][r] = s;
        tm[r] = fmaxf(tm[r], s);
      }
#pragma unroll
    for (int r = 0; r < 4; ++r) {
      tm[r] = fmaxf(tm[r], __shfl_xor(tm[r], 1));
      tm[r] = fmaxf(tm[r], __shfl_xor(tm[r], 2));
      tm[r] = fmaxf(tm[r], __shfl_xor(tm[r], 4));
      tm[r] = fmaxf(tm[r], __shfl_xor(tm[r], 8));
    }
    int need = 0;
#pragma unroll
    for (int r = 0; r < 4; ++r) need |= (tm[r] > m_run[r] + 8.0f);
    if (__any(need)) {
#pragma unroll
      for (int r = 0; r < 4; ++r) {
        const float mn = fmaxf(m_run[r], tm[r]);
        const float corr = ex2(m_run[r] - mn);
        m_run[r] = mn;
        l_run[r] *= corr;
#pragma unroll
        for (int n = 0; n < 4; ++n) oacc[n][r] *= corr;
      }
    }
    float rs[4] = {0.f, 0.f, 0.f, 0.f};
#pragma unroll
    for (int n = 0; n < 4; ++n)
#pragma unroll
      for (int r = 0; r < 4; ++r) {
        p[n][r] = ex2(p[n][r] - m_run[r]);
        rs[r] += p[n][r];
      }
#pragma unroll
    for (int r = 0; r < 4; ++r) {
      rs[r] += __shfl_xor(rs[r], 1);
      rs[r] += __shfl_xor(rs[r], 2);
      rs[r] += __shfl_xor(rs[r], 4);
      rs[r] += __shfl_xor(rs[r], 8);
      l_run[r] += rs[r];
    }

    // P -> per-wave LDS (swizzled)
    unsigned short* Psw = Ps[wave];
#pragma unroll
    for (int n = 0; n < 4; ++n)
#pragma unroll
      for (int r = 0; r < 4; ++r) {
        const int row = g * 4 + r, col = n * 16 + r15;
        Psw[row * 64 + (((col >> 3) ^ (row & 7)) << 3) + (col & 7)] = f2bf(p[n][r]);
      }

    // O += P V  (same-wave LDS dependency, no barrier needed)
    const unsigned short* Vtc = Vt[cur];
#pragma unroll
    for (int kk = 0; kk < 2; ++kk) {
      short8 ap = *(const short8*)(Psw + r15 * 64 + (((kk * 4 + g) ^ (r15 & 7)) << 3));
#pragma unroll
      for (int n = 0; n < 4; ++n) {
        short8 bv = *(const short8*)(Vtc + (n * 16 + r15) * 64 +
                                     (((kk * 4 + g) ^ (r15 & 7)) << 3));
        oacc[n] = __builtin_amdgcn_mfma_f32_16x16x32_bf16(ap, bv, oacc[n], 0, 0, 0);
      }
    }
  }
#undef STAGE

  // normalize and store o (bf16)
#pragma unroll
  for (int n = 0; n < 4; ++n) {
#pragma unroll
    for (int r = 0; r < 4; ++r) {
      const int row = qrow + g * 4 + r;
      const float v = oacc[n][r] / l_run[r];
      o[(size_t)(b * N_ + row) * C_ + h * D_ + n * 16 + r15] = f2bf(v);
    }
  }
}

// ---------------- launcher ----------------
extern "C" void kernel_launch(void* const* d_in, const int* in_sizes, int n_in,
                              void* d_out, int out_size, void* d_ws, size_t ws_size,
                              hipStream_t stream) {
  const float* x      = (const float*)d_in[0];
  const float* pbias  = (const float*)d_in[1];
  const float* qkv_w  = (const float*)d_in[2];
  const float* qkv_b  = (const float*)d_in[3];
  const float* proj_w = (const float*)d_in[4];
  const float* proj_b = (const float*)d_in[5];
  const float* n1_w   = (const float*)d_in[6];
  const float* n1_b   = (const float*)d_in[7];
  const float* n2_w   = (const float*)d_in[8];
  const float* n2_b   = (const float*)d_in[9];
  const float* fc1_w  = (const float*)d_in[10];
  const float* fc1_b  = (const float*)d_in[11];
  const float* fc2_w  = (const float*)d_in[12];
  const float* fc2_b  = (const float*)d_in[13];
  float* out = (float*)d_out;

  char* ws = (char*)d_ws;
  unsigned short* wt_qkv  = (unsigned short*)(ws + 0);          // 2304x768
  unsigned short* wt_proj = (unsigned short*)(ws + 3538944);    // 768x768
  unsigned short* wt_fc1  = (unsigned short*)(ws + 4718592);    // 3072x768
  unsigned short* wt_fc2  = (unsigned short*)(ws + 9437184);    // 768x3072
  float*          x2      = (float*)(ws + 14155776);            // 4096x768 fp32
  unsigned short* h1      = (unsigned short*)(ws + 26738688);   // 4096x768 bf16
  unsigned short* qkvb    = (unsigned short*)(ws + 33030144);   // 4096x2304 bf16

  wconv<<<dim3(2304 / 32, 768 / 32), 256, 0, stream>>>(qkv_w, wt_qkv, 768, 2304);
  wconv<<<dim3(768 / 32, 768 / 32), 256, 0, stream>>>(proj_w, wt_proj, 768, 768);
  wconv<<<dim3(3072 / 32, 768 / 32), 256, 0, stream>>>(fc1_w, wt_fc1, 768, 3072);
  wconv<<<dim3(768 / 32, 3072 / 32), 256, 0, stream>>>(fc2_w, wt_fc2, 3072, 768);

  ln_kernel<<<M_, 256, 0, stream>>>(x, n1_w, n1_b, h1);
  gemm_bt<false, false, false, true><<<dim3(32, 18), 256, 0, stream>>>(
      h1, wt_qkv, qkv_b, nullptr, nullptr, qkvb, M_, 3 * C_, C_);
  attn_kernel<<<dim3(N_ / 64, B_ * H_), 256, 0, stream>>>(qkvb, pbias, h1);
  gemm_bt<false, true, true, false><<<dim3(32, 6), 256, 0, stream>>>(
      h1, wt_proj, proj_b, x, x2, nullptr, M_, C_, C_);
  ln_kernel<<<M_, 256, 0, stream>>>(x2, n2_w, n2_b, h1);
  gemm_bt<true, false, false, true><<<dim3(32, 24), 256, 0, stream>>>(
      h1, wt_fc1, fc1_b, nullptr, nullptr, qkvb, M_, HID_, C_);
  gemm_bt<false, true, true, false><<<dim3(32, 6), 256, 0, stream>>>(
      qkvb, wt_fc2, fc2_b, x2, out, nullptr, M_, C_, HID_);
}

// Round 3
// 227.373 us; speedup vs baseline: 1.1985x; 1.0419x over previous
//
#include <hip/hip_runtime.h>
#include <hip/hip_bf16.h>
#include <cstdint>
#include <cstddef>

// Problem dims (fixed)
#define B_   4
#define N_   1024
#define C_   768
#define H_   12
#define D_   64
#define HID_ 3072
#define M_   4096  // B*N

typedef __attribute__((ext_vector_type(8))) short short8;
typedef __attribute__((ext_vector_type(8))) unsigned short ushort8;
typedef __attribute__((ext_vector_type(4))) float f32x4;

__device__ __forceinline__ void gload16(const void* g, void* l) {
  __builtin_amdgcn_global_load_lds(
      (const __attribute__((address_space(1))) void*)g,
      (__attribute__((address_space(3))) void*)l, 16, 0, 0);
}

__device__ __forceinline__ unsigned short f2bf(float f) {
  __hip_bfloat16 h = __float2bfloat16(f);
  return __builtin_bit_cast(unsigned short, h);
}
__device__ __forceinline__ float bf2f(unsigned short u) {
  unsigned int x = ((unsigned int)u) << 16;
  return __builtin_bit_cast(float, x);
}
__device__ __forceinline__ float ex2(float x) {
  float r;
  asm("v_exp_f32 %0, %1" : "=v"(r) : "v"(x));
  return r;
}

// ---------------- weight fp32 -> bf16 transpose ----------------
__global__ __launch_bounds__(256) void wconv(const float* __restrict__ W,
                                             unsigned short* __restrict__ Wt,
                                             int K, int Nn) {
  __shared__ float tile[32][33];
  const int tx = threadIdx.x & 31, ty = threadIdx.x >> 5;  // 32 x 8
  const int n0 = blockIdx.x * 32, k0 = blockIdx.y * 32;
#pragma unroll
  for (int i = 0; i < 32; i += 8)
    tile[ty + i][tx] = W[(size_t)(k0 + ty + i) * Nn + n0 + tx];
  __syncthreads();
#pragma unroll
  for (int i = 0; i < 32; i += 8)
    Wt[(size_t)(n0 + ty + i) * K + k0 + tx] = f2bf(tile[tx][ty + i]);
}

// ---------------- LayerNorm (fp32 in -> bf16 out) ----------------
__global__ __launch_bounds__(256) void ln_kernel(const float* __restrict__ x,
                                                 const float* __restrict__ w,
                                                 const float* __restrict__ b,
                                                 unsigned short* __restrict__ out) {
  __shared__ float sbuf[8];
  const int row = blockIdx.x;
  const int t = threadIdx.x;
  const float* xr = x + (size_t)row * C_;
  float v0 = xr[t], v1 = xr[t + 256], v2 = xr[t + 512];
  float s = v0 + v1 + v2;
  float ss = v0 * v0 + v1 * v1 + v2 * v2;
#pragma unroll
  for (int m = 32; m >= 1; m >>= 1) {
    s += __shfl_xor(s, m);
    ss += __shfl_xor(ss, m);
  }
  const int wave = t >> 6, lane = t & 63;
  if (lane == 0) { sbuf[wave] = s; sbuf[4 + wave] = ss; }
  __syncthreads();
  s = sbuf[0] + sbuf[1] + sbuf[2] + sbuf[3];
  ss = sbuf[4] + sbuf[5] + sbuf[6] + sbuf[7];
  const float mu = s * (1.f / C_);
  const float var = ss * (1.f / C_) - mu * mu;
  const float rstd = rsqrtf(var + 1e-6f);
  unsigned short* o = out + (size_t)row * C_;
  o[t]       = f2bf((v0 - mu) * rstd * w[t]       + b[t]);
  o[t + 256] = f2bf((v1 - mu) * rstd * w[t + 256] + b[t + 256]);
  o[t + 512] = f2bf((v2 - mu) * rstd * w[t + 512] + b[t + 512]);
}

// ---------------- GEMM: C = A[M,K] * Bt[N,K]^T + bias, fused epilogue ----------
// 128x128 tile, BK=32, 4 waves. Depth-3 prefetch pipeline, counted vmcnt
// (never drained to 0 in steady state), raw s_barrier. 4 LDS buffers (64KB).
// Grid is always (32, Nn/128); bijective XCD swizzle on the flat block id.
template <bool GELU, bool RES, bool OUTF, bool OUTB>
__global__ __launch_bounds__(256) void gemm_bt(const unsigned short* __restrict__ A,
                                               const unsigned short* __restrict__ Bt,
                                               const float* __restrict__ bias,
                                               const float* __restrict__ res,
                                               float* __restrict__ outF,
                                               unsigned short* __restrict__ outB,
                                               int M, int Nn, int K) {
  __shared__ unsigned short As[4][128 * 32];
  __shared__ unsigned short Bs[4][128 * 32];
  const int t = threadIdx.x;
  const int lane = t & 63;
  const int wave = t >> 6;
  const int wm = wave >> 1, wn = wave & 1;
  const int r15 = lane & 15, g = lane >> 4;

  // XCD-aware bijective swizzle (all our grids have nwg % 8 == 0)
  const int orig = blockIdx.y * 32 + blockIdx.x;
  const int nwg = gridDim.y * 32;
  const int swz = (orig & 7) * (nwg >> 3) + (orig >> 3);
  const int bm = swz & 31, bn = swz >> 5;

  f32x4 acc[4][4];
#pragma unroll
  for (int m = 0; m < 4; ++m)
#pragma unroll
    for (int n = 0; n < 4; ++n) acc[m][n] = (f32x4){0.f, 0.f, 0.f, 0.f};

  const unsigned short* ga0 = A + (size_t)(bm * 128 + (t >> 2)) * K + (t & 3) * 8;
  const unsigned short* gb0 = Bt + (size_t)(bn * 128 + (t >> 2)) * K + (t & 3) * 8;

#define GSTAGE(kt_, buf_)                                                \
  {                                                                      \
    const unsigned short* ga = ga0 + (kt_)*32;                           \
    const unsigned short* gb = gb0 + (kt_)*32;                           \
    gload16(ga, (char*)As[buf_] + wave * 1024);                          \
    gload16(ga + (size_t)64 * K, (char*)As[buf_] + wave * 1024 + 4096);  \
    gload16(gb, (char*)Bs[buf_] + wave * 1024);                          \
    gload16(gb + (size_t)64 * K, (char*)Bs[buf_] + wave * 1024 + 4096);  \
  }

  const int nk = K >> 5;  // always >= 24
  GSTAGE(0, 0);
  GSTAGE(1, 1);
  GSTAGE(2, 2);

  for (int kt = 0; kt < nk; ++kt) {
    const int rem = nk - kt;
    if (rem >= 3)
      asm volatile("s_waitcnt vmcnt(8)" ::: "memory");
    else if (rem == 2)
      asm volatile("s_waitcnt vmcnt(4)" ::: "memory");
    else
      asm volatile("s_waitcnt vmcnt(0)" ::: "memory");
    __builtin_amdgcn_s_barrier();

    const int buf = kt & 3;
    short8 af[4], bf[4];
#pragma unroll
    for (int m = 0; m < 4; ++m)
      af[m] = *(const short8*)(As[buf] + (wm * 64 + m * 16 + r15) * 32 + g * 8);
#pragma unroll
    for (int n = 0; n < 4; ++n)
      bf[n] = *(const short8*)(Bs[buf] + (wn * 64 + n * 16 + r15) * 32 + g * 8);

    if (kt + 3 < nk) GSTAGE(kt + 3, (kt + 3) & 3);

    asm volatile("s_waitcnt lgkmcnt(0)" ::: "memory");
    __builtin_amdgcn_sched_barrier(0);
#pragma unroll
    for (int m = 0; m < 4; ++m)
#pragma unroll
      for (int n = 0; n < 4; ++n)
        acc[m][n] = __builtin_amdgcn_mfma_f32_16x16x32_bf16(af[m], bf[n], acc[m][n], 0, 0, 0);
  }
#undef GSTAGE

#pragma unroll
  for (int m = 0; m < 4; ++m) {
#pragma unroll
    for (int n = 0; n < 4; ++n) {
#pragma unroll
      for (int r = 0; r < 4; ++r) {
        const int row = bm * 128 + wm * 64 + m * 16 + g * 4 + r;
        const int col = bn * 128 + wn * 64 + n * 16 + r15;
        float v = acc[m][n][r] + bias[col];
        if (GELU) v = 0.5f * v * (1.f + erff(v * 0.70710678118654752f));
        if (RES) v += res[(size_t)row * Nn + col];
        if (OUTF) outF[(size_t)row * Nn + col] = v;
        if (OUTB) outB[(size_t)row * Nn + col] = f2bf(v);
      }
    }
  }
}

// ---------------- fused biased attention (swizzled LDS, double-buffered) -------
// qkv: [M_, 3*C_] bf16; pbias: [B,N,N] fp32; o: [M_, C_] bf16
// grid: (N/64, B*H); block: 256 (4 waves x 16 q-rows)
__global__ __launch_bounds__(256) void attn_kernel(const unsigned short* __restrict__ qkv,
                                                   const float* __restrict__ pbias,
                                                   unsigned short* __restrict__ o) {
  __shared__ unsigned short Ks[2][64 * 64];
  __shared__ unsigned short Vt[2][64 * 64];
  __shared__ unsigned short Ps[4][16 * 64];
  const int t = threadIdx.x, lane = t & 63, wave = t >> 6;
  const int bh = blockIdx.y;
  const int b = bh / H_, h = bh % H_;
  const int q0 = blockIdx.x * 64;
  const int r15 = lane & 15, g = lane >> 4;
  const int qrow = q0 + wave * 16;
  const float LOG2E = 1.44269504088896f;
  const float QS = 0.125f * 1.44269504088896f;  // SCALE * log2(e)

  short8 aq[2];
  {
    const unsigned short* qp =
        qkv + (size_t)(b * N_ + qrow + r15) * (3 * C_) + h * D_ + g * 8;
    const ushort8 r0 = *(const ushort8*)qp;
    const ushort8 r1 = *(const ushort8*)(qp + 32);
#pragma unroll
    for (int j = 0; j < 8; ++j) {
      aq[0][j] = (short)f2bf(bf2f(r0[j]) * QS);
      aq[1][j] = (short)f2bf(bf2f(r1[j]) * QS);
    }
  }

  f32x4 oacc[4];
#pragma unroll
  for (int n = 0; n < 4; ++n) oacc[n] = (f32x4){0.f, 0.f, 0.f, 0.f};
  float m_run[4], l_run[4];
#pragma unroll
  for (int r = 0; r < 4; ++r) { m_run[r] = -1e30f; l_run[r] = 0.f; }

  const unsigned short* kbase = qkv + (size_t)b * N_ * (3 * C_) + C_ + h * D_;
  const unsigned short* vbase = qkv + (size_t)b * N_ * (3 * C_) + 2 * C_ + h * D_;
  const float* bb = pbias + (size_t)b * N_ * N_;

  const int krow = t >> 3;
  const int kchunk = (t & 7) ^ (krow & 7);
  const int vp = t & 31;
  const int vq = t >> 5;
  const int vkey = vp * 2, vd0 = vq * 8;

#define STAGE(kb_, nb_)                                                              \
  {                                                                                  \
    const unsigned short* kg =                                                       \
        kbase + (size_t)((kb_)*64 + krow) * (3 * C_) + kchunk * 8;                   \
    gload16(kg, (char*)Ks[nb_] + wave * 1024);                                       \
    gload16(kg + (size_t)32 * (3 * C_), (char*)Ks[nb_] + wave * 1024 + 4096);        \
    const unsigned short* vg = vbase + (size_t)((kb_)*64 + vkey) * (3 * C_) + vd0;   \
    const ushort8 va = *(const ushort8*)vg;                                          \
    const ushort8 vb2 = *(const ushort8*)(vg + 3 * C_);                              \
    char* vdst = (char*)Vt[nb_];                                                     \
    _Pragma("unroll") for (int j = 0; j < 8; ++j) {                                  \
      const int d = vd0 + j;                                                         \
      const unsigned int pack = (unsigned int)va[j] | ((unsigned int)vb2[j] << 16);  \
      *(unsigned int*)(vdst + d * 128 + (((vp >> 2) ^ (d & 7)) << 4) +               \
                       (vp & 3) * 4) = pack;                                         \
    }                                                                                \
  }

  STAGE(0, 0);

  for (int kb = 0; kb < N_ / 64; ++kb) {
    const int cur = kb & 1;
    __syncthreads();
    if (kb + 1 < N_ / 64) STAGE(kb + 1, cur ^ 1);

    float bvv[4][4];
#pragma unroll
    for (int n = 0; n < 4; ++n)
#pragma unroll
      for (int r = 0; r < 4; ++r)
        bvv[n][r] = bb[(size_t)(qrow + g * 4 + r) * N_ + kb * 64 + n * 16 + r15];

    const unsigned short* Ksc = Ks[cur];
    f32x4 sacc[4];
#pragma unroll
    for (int n = 0; n < 4; ++n) sacc[n] = (f32x4){0.f, 0.f, 0.f, 0.f};
#pragma unroll
    for (int kk = 0; kk < 2; ++kk) {
#pragma unroll
      for (int n = 0; n < 4; ++n) {
        short8 bk = *(const short8*)(Ksc + (n * 16 + r15) * 64 +
                                     (((kk * 4 + g) ^ (r15 & 7)) << 3));
        sacc[n] = __builtin_amdgcn_mfma_f32_16x16x32_bf16(aq[kk], bk, sacc[n], 0, 0, 0);
      }
    }

    float p[4][4], tm[4];
#pragma unroll
    for (int r = 0; r < 4; ++r) tm[r] = -3e38f;
#pragma unroll
    for (int n = 0; n < 4; ++n)
#pragma unroll
      for (int r = 0; r < 4; ++r) {
        const float s = fmaf(bvv[n][r], LOG2E, sacc[n][r]);
        p[n][r] = s;
        tm[r] = fmaxf(tm[r], s);
      }
#pragma unroll
    for (int r = 0; r < 4; ++r) {
      tm[r] = fmaxf(tm[r], __shfl_xor(tm[r], 1));
      tm[r] = fmaxf(tm[r], __shfl_xor(tm[r], 2));
      tm[r] = fmaxf(tm[r], __shfl_xor(tm[r], 4));
      tm[r] = fmaxf(tm[r], __shfl_xor(tm[r], 8));
    }
    int need = 0;
#pragma unroll
    for (int r = 0; r < 4; ++r) need |= (tm[r] > m_run[r] + 8.0f);
    if (__any(need)) {
#pragma unroll
      for (int r = 0; r < 4; ++r) {
        const float mn = fmaxf(m_run[r], tm[r]);
        const float corr = ex2(m_run[r] - mn);
        m_run[r] = mn;
        l_run[r] *= corr;
#pragma unroll
        for (int n = 0; n < 4; ++n) oacc[n][r] *= corr;
      }
    }
    float rs[4] = {0.f, 0.f, 0.f, 0.f};
#pragma unroll
    for (int n = 0; n < 4; ++n)
#pragma unroll
      for (int r = 0; r < 4; ++r) {
        p[n][r] = ex2(p[n][r] - m_run[r]);
        rs[r] += p[n][r];
      }
#pragma unroll
    for (int r = 0; r < 4; ++r) {
      rs[r] += __shfl_xor(rs[r], 1);
      rs[r] += __shfl_xor(rs[r], 2);
      rs[r] += __shfl_xor(rs[r], 4);
      rs[r] += __shfl_xor(rs[r], 8);
      l_run[r] += rs[r];
    }

    unsigned short* Psw = Ps[wave];
#pragma unroll
    for (int n = 0; n < 4; ++n)
#pragma unroll
      for (int r = 0; r < 4; ++r) {
        const int row = g * 4 + r, col = n * 16 + r15;
        Psw[row * 64 + (((col >> 3) ^ (row & 7)) << 3) + (col & 7)] = f2bf(p[n][r]);
      }

    const unsigned short* Vtc = Vt[cur];
#pragma unroll
    for (int kk = 0; kk < 2; ++kk) {
      short8 ap = *(const short8*)(Psw + r15 * 64 + (((kk * 4 + g) ^ (r15 & 7)) << 3));
#pragma unroll
      for (int n = 0; n < 4; ++n) {
        short8 bv = *(const short8*)(Vtc + (n * 16 + r15) * 64 +
                                     (((kk * 4 + g) ^ (r15 & 7)) << 3));
        oacc[n] = __builtin_amdgcn_mfma_f32_16x16x32_bf16(ap, bv, oacc[n], 0, 0, 0);
      }
    }
  }
#undef STAGE

#pragma unroll
  for (int n = 0; n < 4; ++n) {
#pragma unroll
    for (int r = 0; r < 4; ++r) {
      const int row = qrow + g * 4 + r;
      const float v = oacc[n][r] / l_run[r];
      o[(size_t)(b * N_ + row) * C_ + h * D_ + n * 16 + r15] = f2bf(v);
    }
  }
}

// ---------------- launcher ----------------
extern "C" void kernel_launch(void* const* d_in, const int* in_sizes, int n_in,
                              void* d_out, int out_size, void* d_ws, size_t ws_size,
                              hipStream_t stream) {
  const float* x      = (const float*)d_in[0];
  const float* pbias  = (const float*)d_in[1];
  const float* qkv_w  = (const float*)d_in[2];
  const float* qkv_b  = (const float*)d_in[3];
  const float* proj_w = (const float*)d_in[4];
  const float* proj_b = (const float*)d_in[5];
  const float* n1_w   = (const float*)d_in[6];
  const float* n1_b   = (const float*)d_in[7];
  const float* n2_w   = (const float*)d_in[8];
  const float* n2_b   = (const float*)d_in[9];
  const float* fc1_w  = (const float*)d_in[10];
  const float* fc1_b  = (const float*)d_in[11];
  const float* fc2_w  = (const float*)d_in[12];
  const float* fc2_b  = (const float*)d_in[13];
  float* out = (float*)d_out;

  char* ws = (char*)d_ws;
  unsigned short* wt_qkv  = (unsigned short*)(ws + 0);          // 2304x768
  unsigned short* wt_proj = (unsigned short*)(ws + 3538944);    // 768x768
  unsigned short* wt_fc1  = (unsigned short*)(ws + 4718592);    // 3072x768
  unsigned short* wt_fc2  = (unsigned short*)(ws + 9437184);    // 768x3072
  float*          x2      = (float*)(ws + 14155776);            // 4096x768 fp32
  unsigned short* h1      = (unsigned short*)(ws + 26738688);   // 4096x768 bf16
  unsigned short* qkvb    = (unsigned short*)(ws + 33030144);   // 4096x2304 bf16

  wconv<<<dim3(2304 / 32, 768 / 32), 256, 0, stream>>>(qkv_w, wt_qkv, 768, 2304);
  wconv<<<dim3(768 / 32, 768 / 32), 256, 0, stream>>>(proj_w, wt_proj, 768, 768);
  wconv<<<dim3(3072 / 32, 768 / 32), 256, 0, stream>>>(fc1_w, wt_fc1, 768, 3072);
  wconv<<<dim3(768 / 32, 3072 / 32), 256, 0, stream>>>(fc2_w, wt_fc2, 3072, 768);

  ln_kernel<<<M_, 256, 0, stream>>>(x, n1_w, n1_b, h1);
  gemm_bt<false, false, false, true><<<dim3(32, 18), 256, 0, stream>>>(
      h1, wt_qkv, qkv_b, nullptr, nullptr, qkvb, M_, 3 * C_, C_);
  attn_kernel<<<dim3(N_ / 64, B_ * H_), 256, 0, stream>>>(qkvb, pbias, h1);
  gemm_bt<false, true, true, false><<<dim3(32, 6), 256, 0, stream>>>(
      h1, wt_proj, proj_b, x, x2, nullptr, M_, C_, C_);
  ln_kernel<<<M_, 256, 0, stream>>>(x2, n2_w, n2_b, h1);
  gemm_bt<true, false, false, true><<<dim3(32, 24), 256, 0, stream>>>(
      h1, wt_fc1, fc1_b, nullptr, nullptr, qkvb, M_, HID_, C_);
  gemm_bt<false, true, true, false><<<dim3(32, 6), 256, 0, stream>>>(
      qkvb, wt_fc2, fc2_b, x2, out, nullptr, M_, C_, HID_);
}

// Round 4
// 222.644 us; speedup vs baseline: 1.2240x; 1.0212x over previous
//
#include <hip/hip_runtime.h>
#include <hip/hip_bf16.h>
#include <cstdint>
#include <cstddef>

// Problem dims (fixed)
#define B_   4
#define N_   1024
#define C_   768
#define H_   12
#define D_   64
#define HID_ 3072
#define M_   4096  // B*N

typedef __attribute__((ext_vector_type(8))) short short8;
typedef __attribute__((ext_vector_type(8))) unsigned short ushort8;
typedef __attribute__((ext_vector_type(4))) float f32x4;

__device__ __forceinline__ void gload16(const void* g, void* l) {
  __builtin_amdgcn_global_load_lds(
      (const __attribute__((address_space(1))) void*)g,
      (__attribute__((address_space(3))) void*)l, 16, 0, 0);
}

__device__ __forceinline__ unsigned short f2bf(float f) {
  __hip_bfloat16 h = __float2bfloat16(f);
  return __builtin_bit_cast(unsigned short, h);
}
__device__ __forceinline__ float bf2f(unsigned short u) {
  unsigned int x = ((unsigned int)u) << 16;
  return __builtin_bit_cast(float, x);
}
__device__ __forceinline__ float ex2(float x) {
  float r;
  asm("v_exp_f32 %0, %1" : "=v"(r) : "v"(x));
  return r;
}

// ---------------- weight fp32 -> bf16 transpose ----------------
__global__ __launch_bounds__(256) void wconv(const float* __restrict__ W,
                                             unsigned short* __restrict__ Wt,
                                             int K, int Nn) {
  __shared__ float tile[32][33];
  const int tx = threadIdx.x & 31, ty = threadIdx.x >> 5;  // 32 x 8
  const int n0 = blockIdx.x * 32, k0 = blockIdx.y * 32;
#pragma unroll
  for (int i = 0; i < 32; i += 8)
    tile[ty + i][tx] = W[(size_t)(k0 + ty + i) * Nn + n0 + tx];
  __syncthreads();
#pragma unroll
  for (int i = 0; i < 32; i += 8)
    Wt[(size_t)(n0 + ty + i) * K + k0 + tx] = f2bf(tile[tx][ty + i]);
}

// ---------------- LayerNorm (fp32 in -> bf16 out) ----------------
__global__ __launch_bounds__(256) void ln_kernel(const float* __restrict__ x,
                                                 const float* __restrict__ w,
                                                 const float* __restrict__ b,
                                                 unsigned short* __restrict__ out) {
  __shared__ float sbuf[8];
  const int row = blockIdx.x;
  const int t = threadIdx.x;
  const float* xr = x + (size_t)row * C_;
  float v0 = xr[t], v1 = xr[t + 256], v2 = xr[t + 512];
  float s = v0 + v1 + v2;
  float ss = v0 * v0 + v1 * v1 + v2 * v2;
#pragma unroll
  for (int m = 32; m >= 1; m >>= 1) {
    s += __shfl_xor(s, m);
    ss += __shfl_xor(ss, m);
  }
  const int wave = t >> 6, lane = t & 63;
  if (lane == 0) { sbuf[wave] = s; sbuf[4 + wave] = ss; }
  __syncthreads();
  s = sbuf[0] + sbuf[1] + sbuf[2] + sbuf[3];
  ss = sbuf[4] + sbuf[5] + sbuf[6] + sbuf[7];
  const float mu = s * (1.f / C_);
  const float var = ss * (1.f / C_) - mu * mu;
  const float rstd = rsqrtf(var + 1e-6f);
  unsigned short* o = out + (size_t)row * C_;
  o[t]       = f2bf((v0 - mu) * rstd * w[t]       + b[t]);
  o[t + 256] = f2bf((v1 - mu) * rstd * w[t + 256] + b[t + 256]);
  o[t + 512] = f2bf((v2 - mu) * rstd * w[t + 512] + b[t + 512]);
}

// ---------------- GEMM: C = A[M,K] * Bt[N,K]^T + bias, fused epilogue ----------
// 128x128 tile, BK=32, 4 waves. Depth-4 prefetch, 5 LDS buffers (80KB),
// counted vmcnt (12/8/4/0), raw s_barrier, setprio around MFMA.
// XCD stripe swizzle: xcd = orig&7 owns bm stripe xcd*4..xcd*4+3 (A L2-fit),
// bn varies fast (back-to-back W panel reuse).
template <bool GELU, bool RES, bool OUTF, bool OUTB>
__global__ __launch_bounds__(256) void gemm_bt(const unsigned short* __restrict__ A,
                                               const unsigned short* __restrict__ Bt,
                                               const float* __restrict__ bias,
                                               const float* __restrict__ res,
                                               float* __restrict__ outF,
                                               unsigned short* __restrict__ outB,
                                               int M, int Nn, int K) {
  __shared__ unsigned short As[5][128 * 32];
  __shared__ unsigned short Bs[5][128 * 32];
  const int t = threadIdx.x;
  const int lane = t & 63;
  const int wave = t >> 6;
  const int wm = wave >> 1, wn = wave & 1;
  const int r15 = lane & 15, g = lane >> 4;

  // XCD stripe swizzle (gridDim.x == 32 always; M/128 == 32)
  const int orig = blockIdx.y * 32 + blockIdx.x;
  const int xcd = orig & 7;
  const int j = orig >> 3;
  const int bm = xcd * 4 + (j & 3);
  const int bn = j >> 2;

  f32x4 acc[4][4];
#pragma unroll
  for (int m = 0; m < 4; ++m)
#pragma unroll
    for (int n = 0; n < 4; ++n) acc[m][n] = (f32x4){0.f, 0.f, 0.f, 0.f};

  const unsigned short* ga0 = A + (size_t)(bm * 128 + (t >> 2)) * K + (t & 3) * 8;
  const unsigned short* gb0 = Bt + (size_t)(bn * 128 + (t >> 2)) * K + (t & 3) * 8;

#define GSTAGE(kt_, buf_)                                                \
  {                                                                      \
    const unsigned short* ga = ga0 + (kt_)*32;                           \
    const unsigned short* gb = gb0 + (kt_)*32;                           \
    gload16(ga, (char*)As[buf_] + wave * 1024);                          \
    gload16(ga + (size_t)64 * K, (char*)As[buf_] + wave * 1024 + 4096);  \
    gload16(gb, (char*)Bs[buf_] + wave * 1024);                          \
    gload16(gb + (size_t)64 * K, (char*)Bs[buf_] + wave * 1024 + 4096);  \
  }

  const int nk = K >> 5;  // >= 24 for all our shapes
  GSTAGE(0, 0);
  GSTAGE(1, 1);
  GSTAGE(2, 2);
  GSTAGE(3, 3);

  int rd = 0;
  for (int kt = 0; kt < nk; ++kt) {
    const int rem = nk - kt;
    if (rem >= 4)
      asm volatile("s_waitcnt vmcnt(12)" ::: "memory");
    else if (rem == 3)
      asm volatile("s_waitcnt vmcnt(8)" ::: "memory");
    else if (rem == 2)
      asm volatile("s_waitcnt vmcnt(4)" ::: "memory");
    else
      asm volatile("s_waitcnt vmcnt(0)" ::: "memory");
    __builtin_amdgcn_s_barrier();

    short8 af[4], bf[4];
#pragma unroll
    for (int m = 0; m < 4; ++m)
      af[m] = *(const short8*)(As[rd] + (wm * 64 + m * 16 + r15) * 32 + g * 8);
#pragma unroll
    for (int n = 0; n < 4; ++n)
      bf[n] = *(const short8*)(Bs[rd] + (wn * 64 + n * 16 + r15) * 32 + g * 8);

    if (kt + 4 < nk) {
      const int wr = (rd == 0) ? 4 : rd - 1;  // == (kt+4)%5
      GSTAGE(kt + 4, wr);
    }

    asm volatile("s_waitcnt lgkmcnt(0)" ::: "memory");
    __builtin_amdgcn_sched_barrier(0);
    __builtin_amdgcn_s_setprio(1);
#pragma unroll
    for (int m = 0; m < 4; ++m)
#pragma unroll
      for (int n = 0; n < 4; ++n)
        acc[m][n] = __builtin_amdgcn_mfma_f32_16x16x32_bf16(af[m], bf[n], acc[m][n], 0, 0, 0);
    __builtin_amdgcn_s_setprio(0);
    rd = (rd == 4) ? 0 : rd + 1;
  }
#undef GSTAGE

#pragma unroll
  for (int m = 0; m < 4; ++m) {
#pragma unroll
    for (int n = 0; n < 4; ++n) {
#pragma unroll
      for (int r = 0; r < 4; ++r) {
        const int row = bm * 128 + wm * 64 + m * 16 + g * 4 + r;
        const int col = bn * 128 + wn * 64 + n * 16 + r15;
        float v = acc[m][n][r] + bias[col];
        if (GELU) v = 0.5f * v * (1.f + erff(v * 0.70710678118654752f));
        if (RES) v += res[(size_t)row * Nn + col];
        if (OUTF) outF[(size_t)row * Nn + col] = v;
        if (OUTB) outB[(size_t)row * Nn + col] = f2bf(v);
      }
    }
  }
}

// ---------------- fused biased attention ----------------
// Swizzled LDS (conflict-free), double-buffered K/V, async-split V staging
// (issue-early/write-late), bias prefetched one tile ahead into registers.
// grid: (N/64, B*H); block: 256 (4 waves x 16 q-rows)
__global__ __launch_bounds__(256) void attn_kernel(const unsigned short* __restrict__ qkv,
                                                   const float* __restrict__ pbias,
                                                   unsigned short* __restrict__ o) {
  __shared__ unsigned short Ks[2][64 * 64];
  __shared__ unsigned short Vt[2][64 * 64];
  __shared__ unsigned short Ps[4][16 * 64];
  const int t = threadIdx.x, lane = t & 63, wave = t >> 6;
  const int bh = blockIdx.y;
  const int b = bh / H_, h = bh % H_;
  const int q0 = blockIdx.x * 64;
  const int r15 = lane & 15, g = lane >> 4;
  const int qrow = q0 + wave * 16;
  const float LOG2E = 1.44269504088896f;
  const float QS = 0.125f * 1.44269504088896f;  // SCALE * log2(e)
  const int NT = N_ / 64;

  short8 aq[2];
  {
    const unsigned short* qp =
        qkv + (size_t)(b * N_ + qrow + r15) * (3 * C_) + h * D_ + g * 8;
    const ushort8 r0 = *(const ushort8*)qp;
    const ushort8 r1 = *(const ushort8*)(qp + 32);
#pragma unroll
    for (int j = 0; j < 8; ++j) {
      aq[0][j] = (short)f2bf(bf2f(r0[j]) * QS);
      aq[1][j] = (short)f2bf(bf2f(r1[j]) * QS);
    }
  }

  f32x4 oacc[4];
#pragma unroll
  for (int n = 0; n < 4; ++n) oacc[n] = (f32x4){0.f, 0.f, 0.f, 0.f};
  float m_run[4], l_run[4];
#pragma unroll
  for (int r = 0; r < 4; ++r) { m_run[r] = -1e30f; l_run[r] = 0.f; }

  const unsigned short* kbase = qkv + (size_t)b * N_ * (3 * C_) + C_ + h * D_;
  const unsigned short* vbase = qkv + (size_t)b * N_ * (3 * C_) + 2 * C_ + h * D_;
  const float* bb = pbias + (size_t)b * N_ * N_;

  const int krow = t >> 3;
  const int kchunk = (t & 7) ^ (krow & 7);
  const int vp = t & 31;
  const int vq = t >> 5;
  const int vkey = vp * 2, vd0 = vq * 8;

#define KSTAGE(kb_, nb_)                                                       \
  {                                                                            \
    const unsigned short* kg =                                                 \
        kbase + (size_t)((kb_)*64 + krow) * (3 * C_) + kchunk * 8;             \
    gload16(kg, (char*)Ks[nb_] + wave * 1024);                                 \
    gload16(kg + (size_t)32 * (3 * C_), (char*)Ks[nb_] + wave * 1024 + 4096);  \
  }

#define VWRITE(nb_, va_, vb_)                                                        \
  {                                                                                  \
    char* vdst = (char*)Vt[nb_];                                                     \
    _Pragma("unroll") for (int jj = 0; jj < 8; ++jj) {                               \
      const int d = vd0 + jj;                                                        \
      const unsigned int pack =                                                      \
          (unsigned int)(va_)[jj] | ((unsigned int)(vb_)[jj] << 16);                 \
      *(unsigned int*)(vdst + d * 128 + (((vp >> 2) ^ (d & 7)) << 4) +               \
                       (vp & 3) * 4) = pack;                                         \
    }                                                                                \
  }

  // Prologue: stage tile 0 fully; prefetch bias for tile 0.
  {
    KSTAGE(0, 0);
    const unsigned short* vg = vbase + (size_t)vkey * (3 * C_) + vd0;
    const ushort8 va = *(const ushort8*)vg;
    const ushort8 vb2 = *(const ushort8*)(vg + 3 * C_);
    VWRITE(0, va, vb2);
  }
  float bcur[4][4], bnext[4][4];
#pragma unroll
  for (int n = 0; n < 4; ++n)
#pragma unroll
    for (int r = 0; r < 4; ++r)
      bcur[n][r] = bb[(size_t)(qrow + g * 4 + r) * N_ + n * 16 + r15];

  for (int kb = 0; kb < NT; ++kb) {
    const int cur = kb & 1;
    const int nxt = cur ^ 1;
    __syncthreads();  // tile kb staged & visible

    ushort8 va, vb2;
    const bool more = (kb + 1 < NT);
    if (more) {
      // issue-early: K direct-to-LDS, V global->reg, bias global->reg
      KSTAGE(kb + 1, nxt);
      const unsigned short* vg =
          vbase + (size_t)((kb + 1) * 64 + vkey) * (3 * C_) + vd0;
      va = *(const ushort8*)vg;
      vb2 = *(const ushort8*)(vg + 3 * C_);
#pragma unroll
      for (int n = 0; n < 4; ++n)
#pragma unroll
        for (int r = 0; r < 4; ++r)
          bnext[n][r] =
              bb[(size_t)(qrow + g * 4 + r) * N_ + (kb + 1) * 64 + n * 16 + r15];
    }

    // S = Q K^T (16 x 64 per wave), log2-scaled domain
    const unsigned short* Ksc = Ks[cur];
    f32x4 sacc[4];
#pragma unroll
    for (int n = 0; n < 4; ++n) sacc[n] = (f32x4){0.f, 0.f, 0.f, 0.f};
    __builtin_amdgcn_s_setprio(1);
#pragma unroll
    for (int kk = 0; kk < 2; ++kk) {
#pragma unroll
      for (int n = 0; n < 4; ++n) {
        short8 bk = *(const short8*)(Ksc + (n * 16 + r15) * 64 +
                                     (((kk * 4 + g) ^ (r15 & 7)) << 3));
        sacc[n] = __builtin_amdgcn_mfma_f32_16x16x32_bf16(aq[kk], bk, sacc[n], 0, 0, 0);
      }
    }
    __builtin_amdgcn_s_setprio(0);

    // online softmax (log2 domain, defer-max)
    float p[4][4], tm[4];
#pragma unroll
    for (int r = 0; r < 4; ++r) tm[r] = -3e38f;
#pragma unroll
    for (int n = 0; n < 4; ++n)
#pragma unroll
      for (int r = 0; r < 4; ++r) {
        const float s = fmaf(bcur[n][r], LOG2E, sacc[n][r]);
        p[n][r] = s;
        tm[r] = fmaxf(tm[r], s);
      }
#pragma unroll
    for (int r = 0; r < 4; ++r) {
      tm[r] = fmaxf(tm[r], __shfl_xor(tm[r], 1));
      tm[r] = fmaxf(tm[r], __shfl_xor(tm[r], 2));
      tm[r] = fmaxf(tm[r], __shfl_xor(tm[r], 4));
      tm[r] = fmaxf(tm[r], __shfl_xor(tm[r], 8));
    }
    int need = 0;
#pragma unroll
    for (int r = 0; r < 4; ++r) need |= (tm[r] > m_run[r] + 8.0f);
    if (__any(need)) {
#pragma unroll
      for (int r = 0; r < 4; ++r) {
        const float mn = fmaxf(m_run[r], tm[r]);
        const float corr = ex2(m_run[r] - mn);
        m_run[r] = mn;
        l_run[r] *= corr;
#pragma unroll
        for (int n = 0; n < 4; ++n) oacc[n][r] *= corr;
      }
    }
    float rs[4] = {0.f, 0.f, 0.f, 0.f};
#pragma unroll
    for (int n = 0; n < 4; ++n)
#pragma unroll
      for (int r = 0; r < 4; ++r) {
        p[n][r] = ex2(p[n][r] - m_run[r]);
        rs[r] += p[n][r];
      }
#pragma unroll
    for (int r = 0; r < 4; ++r) {
      rs[r] += __shfl_xor(rs[r], 1);
      rs[r] += __shfl_xor(rs[r], 2);
      rs[r] += __shfl_xor(rs[r], 4);
      rs[r] += __shfl_xor(rs[r], 8);
      l_run[r] += rs[r];
    }

    // P -> per-wave LDS (swizzled)
    unsigned short* Psw = Ps[wave];
#pragma unroll
    for (int n = 0; n < 4; ++n)
#pragma unroll
      for (int r = 0; r < 4; ++r) {
        const int row = g * 4 + r, col = n * 16 + r15;
        Psw[row * 64 + (((col >> 3) ^ (row & 7)) << 3) + (col & 7)] = f2bf(p[n][r]);
      }

    // O += P V  (same-wave LDS dependency, no barrier needed)
    const unsigned short* Vtc = Vt[cur];
    __builtin_amdgcn_s_setprio(1);
#pragma unroll
    for (int kk = 0; kk < 2; ++kk) {
      short8 ap = *(const short8*)(Psw + r15 * 64 + (((kk * 4 + g) ^ (r15 & 7)) << 3));
#pragma unroll
      for (int n = 0; n < 4; ++n) {
        short8 bv = *(const short8*)(Vtc + (n * 16 + r15) * 64 +
                                     (((kk * 4 + g) ^ (r15 & 7)) << 3));
        oacc[n] = __builtin_amdgcn_mfma_f32_16x16x32_bf16(ap, bv, oacc[n], 0, 0, 0);
      }
    }
    __builtin_amdgcn_s_setprio(0);

    if (more) {
      // write-late: V regs (loaded at top of this iter, latency hidden) -> LDS
      VWRITE(nxt, va, vb2);
#pragma unroll
      for (int n = 0; n < 4; ++n)
#pragma unroll
        for (int r = 0; r < 4; ++r) bcur[n][r] = bnext[n][r];
    }
  }
#undef KSTAGE
#undef VWRITE

#pragma unroll
  for (int n = 0; n < 4; ++n) {
#pragma unroll
    for (int r = 0; r < 4; ++r) {
      const int row = qrow + g * 4 + r;
      const float v = oacc[n][r] / l_run[r];
      o[(size_t)(b * N_ + row) * C_ + h * D_ + n * 16 + r15] = f2bf(v);
    }
  }
}

// ---------------- launcher ----------------
extern "C" void kernel_launch(void* const* d_in, const int* in_sizes, int n_in,
                              void* d_out, int out_size, void* d_ws, size_t ws_size,
                              hipStream_t stream) {
  const float* x      = (const float*)d_in[0];
  const float* pbias  = (const float*)d_in[1];
  const float* qkv_w  = (const float*)d_in[2];
  const float* qkv_b  = (const float*)d_in[3];
  const float* proj_w = (const float*)d_in[4];
  const float* proj_b = (const float*)d_in[5];
  const float* n1_w   = (const float*)d_in[6];
  const float* n1_b   = (const float*)d_in[7];
  const float* n2_w   = (const float*)d_in[8];
  const float* n2_b   = (const float*)d_in[9];
  const float* fc1_w  = (const float*)d_in[10];
  const float* fc1_b  = (const float*)d_in[11];
  const float* fc2_w  = (const float*)d_in[12];
  const float* fc2_b  = (const float*)d_in[13];
  float* out = (float*)d_out;

  char* ws = (char*)d_ws;
  unsigned short* wt_qkv  = (unsigned short*)(ws + 0);          // 2304x768
  unsigned short* wt_proj = (unsigned short*)(ws + 3538944);    // 768x768
  unsigned short* wt_fc1  = (unsigned short*)(ws + 4718592);    // 3072x768
  unsigned short* wt_fc2  = (unsigned short*)(ws + 9437184);    // 768x3072
  float*          x2      = (float*)(ws + 14155776);            // 4096x768 fp32
  unsigned short* h1      = (unsigned short*)(ws + 26738688);   // 4096x768 bf16
  unsigned short* qkvb    = (unsigned short*)(ws + 33030144);   // 4096x2304 bf16

  wconv<<<dim3(2304 / 32, 768 / 32), 256, 0, stream>>>(qkv_w, wt_qkv, 768, 2304);
  wconv<<<dim3(768 / 32, 768 / 32), 256, 0, stream>>>(proj_w, wt_proj, 768, 768);
  wconv<<<dim3(3072 / 32, 768 / 32), 256, 0, stream>>>(fc1_w, wt_fc1, 768, 3072);
  wconv<<<dim3(768 / 32, 3072 / 32), 256, 0, stream>>>(fc2_w, wt_fc2, 3072, 768);

  ln_kernel<<<M_, 256, 0, stream>>>(x, n1_w, n1_b, h1);
  gemm_bt<false, false, false, true><<<dim3(32, 18), 256, 0, stream>>>(
      h1, wt_qkv, qkv_b, nullptr, nullptr, qkvb, M_, 3 * C_, C_);
  attn_kernel<<<dim3(N_ / 64, B_ * H_), 256, 0, stream>>>(qkvb, pbias, h1);
  gemm_bt<false, true, true, false><<<dim3(32, 6), 256, 0, stream>>>(
      h1, wt_proj, proj_b, x, x2, nullptr, M_, C_, C_);
  ln_kernel<<<M_, 256, 0, stream>>>(x2, n2_w, n2_b, h1);
  gemm_bt<true, false, false, true><<<dim3(32, 24), 256, 0, stream>>>(
      h1, wt_fc1, fc1_b, nullptr, nullptr, qkvb, M_, HID_, C_);
  gemm_bt<false, true, true, false><<<dim3(32, 6), 256, 0, stream>>>(
      qkvb, wt_fc2, fc2_b, x2, out, nullptr, M_, C_, HID_);
}

// Round 5
// 213.999 us; speedup vs baseline: 1.2734x; 1.0404x over previous
//
#include <hip/hip_runtime.h>
#include <hip/hip_bf16.h>
#include <cstdint>
#include <cstddef>

// Problem dims (fixed)
#define B_   4
#define N_   1024
#define C_   768
#define H_   12
#define D_   64
#define HID_ 3072
#define M_   4096  // B*N

typedef __attribute__((ext_vector_type(8))) short short8;
typedef __attribute__((ext_vector_type(8))) unsigned short ushort8;
typedef __attribute__((ext_vector_type(4))) float f32x4;

__device__ __forceinline__ void gload16(const void* g, void* l) {
  __builtin_amdgcn_global_load_lds(
      (const __attribute__((address_space(1))) void*)g,
      (__attribute__((address_space(3))) void*)l, 16, 0, 0);
}

__device__ __forceinline__ unsigned short f2bf(float f) {
  __hip_bfloat16 h = __float2bfloat16(f);
  return __builtin_bit_cast(unsigned short, h);
}
__device__ __forceinline__ float bf2f(unsigned short u) {
  unsigned int x = ((unsigned int)u) << 16;
  return __builtin_bit_cast(float, x);
}
__device__ __forceinline__ float ex2(float x) {
  float r;
  asm("v_exp_f32 %0, %1" : "=v"(r) : "v"(x));
  return r;
}
__device__ __forceinline__ float frcp(float x) {
  float r;
  asm("v_rcp_f32 %0, %1" : "=v"(r) : "v"(x));
  return r;
}

// ---------------- merged weight fp32 -> bf16 transpose ----------------
// One launch for all four weights. W [K][Nn] fp32 -> Wt [Nn][K] bf16.
// tiles: qkv 72x24=1728 | proj 24x24=576 | fc1 96x24=2304 | fc2 24x96=2304
__global__ __launch_bounds__(256) void wconv_all(
    const float* __restrict__ qkv_w, const float* __restrict__ proj_w,
    const float* __restrict__ fc1_w, const float* __restrict__ fc2_w,
    unsigned short* __restrict__ wt_qkv, unsigned short* __restrict__ wt_proj,
    unsigned short* __restrict__ wt_fc1, unsigned short* __restrict__ wt_fc2) {
  __shared__ float tile[32][33];
  const int bid = blockIdx.x;
  const float* W;
  unsigned short* Wt;
  int K, Nn, bx, by;
  if (bid < 1728) {
    W = qkv_w; Wt = wt_qkv; K = 768; Nn = 2304;
    bx = bid % 72; by = bid / 72;
  } else if (bid < 1728 + 576) {
    const int i = bid - 1728;
    W = proj_w; Wt = wt_proj; K = 768; Nn = 768;
    bx = i % 24; by = i / 24;
  } else if (bid < 1728 + 576 + 2304) {
    const int i = bid - (1728 + 576);
    W = fc1_w; Wt = wt_fc1; K = 768; Nn = 3072;
    bx = i % 96; by = i / 96;
  } else {
    const int i = bid - (1728 + 576 + 2304);
    W = fc2_w; Wt = wt_fc2; K = 3072; Nn = 768;
    bx = i % 24; by = i / 24;
  }
  const int tx = threadIdx.x & 31, ty = threadIdx.x >> 5;  // 32 x 8
  const int n0 = bx * 32, k0 = by * 32;
#pragma unroll
  for (int i = 0; i < 32; i += 8)
    tile[ty + i][tx] = W[(size_t)(k0 + ty + i) * Nn + n0 + tx];
  __syncthreads();
#pragma unroll
  for (int i = 0; i < 32; i += 8)
    Wt[(size_t)(n0 + ty + i) * K + k0 + tx] = f2bf(tile[tx][ty + i]);
}

// ---------------- LayerNorm (fp32 in -> bf16 out) ----------------
__global__ __launch_bounds__(256) void ln_kernel(const float* __restrict__ x,
                                                 const float* __restrict__ w,
                                                 const float* __restrict__ b,
                                                 unsigned short* __restrict__ out) {
  __shared__ float sbuf[8];
  const int row = blockIdx.x;
  const int t = threadIdx.x;
  const float* xr = x + (size_t)row * C_;
  float v0 = xr[t], v1 = xr[t + 256], v2 = xr[t + 512];
  float s = v0 + v1 + v2;
  float ss = v0 * v0 + v1 * v1 + v2 * v2;
#pragma unroll
  for (int m = 32; m >= 1; m >>= 1) {
    s += __shfl_xor(s, m);
    ss += __shfl_xor(ss, m);
  }
  const int wave = t >> 6, lane = t & 63;
  if (lane == 0) { sbuf[wave] = s; sbuf[4 + wave] = ss; }
  __syncthreads();
  s = sbuf[0] + sbuf[1] + sbuf[2] + sbuf[3];
  ss = sbuf[4] + sbuf[5] + sbuf[6] + sbuf[7];
  const float mu = s * (1.f / C_);
  const float var = ss * (1.f / C_) - mu * mu;
  const float rstd = rsqrtf(var + 1e-6f);
  unsigned short* o = out + (size_t)row * C_;
  o[t]       = f2bf((v0 - mu) * rstd * w[t]       + b[t]);
  o[t + 256] = f2bf((v1 - mu) * rstd * w[t + 256] + b[t + 256]);
  o[t + 512] = f2bf((v2 - mu) * rstd * w[t + 512] + b[t + 512]);
}

// ---------------- GEMM: C = A[M,K] * Bt[N,K]^T + bias, fused epilogue ----------
// 128x128 tile, BK=32, 4 waves. Depth-4 prefetch, 5 LDS buffers (80KB),
// counted vmcnt (12/8/4/0), raw s_barrier, setprio around MFMA.
template <bool GELU, bool RES, bool OUTF, bool OUTB>
__global__ __launch_bounds__(256) void gemm_bt(const unsigned short* __restrict__ A,
                                               const unsigned short* __restrict__ Bt,
                                               const float* __restrict__ bias,
                                               const float* __restrict__ res,
                                               float* __restrict__ outF,
                                               unsigned short* __restrict__ outB,
                                               int M, int Nn, int K) {
  __shared__ unsigned short As[5][128 * 32];
  __shared__ unsigned short Bs[5][128 * 32];
  const int t = threadIdx.x;
  const int lane = t & 63;
  const int wave = t >> 6;
  const int wm = wave >> 1, wn = wave & 1;
  const int r15 = lane & 15, g = lane >> 4;

  // XCD stripe swizzle (gridDim.x == 32 always; M/128 == 32)
  const int orig = blockIdx.y * 32 + blockIdx.x;
  const int xcd = orig & 7;
  const int j = orig >> 3;
  const int bm = xcd * 4 + (j & 3);
  const int bn = j >> 2;

  f32x4 acc[4][4];
#pragma unroll
  for (int m = 0; m < 4; ++m)
#pragma unroll
    for (int n = 0; n < 4; ++n) acc[m][n] = (f32x4){0.f, 0.f, 0.f, 0.f};

  const unsigned short* ga0 = A + (size_t)(bm * 128 + (t >> 2)) * K + (t & 3) * 8;
  const unsigned short* gb0 = Bt + (size_t)(bn * 128 + (t >> 2)) * K + (t & 3) * 8;

#define GSTAGE(kt_, buf_)                                                \
  {                                                                      \
    const unsigned short* ga = ga0 + (kt_)*32;                           \
    const unsigned short* gb = gb0 + (kt_)*32;                           \
    gload16(ga, (char*)As[buf_] + wave * 1024);                          \
    gload16(ga + (size_t)64 * K, (char*)As[buf_] + wave * 1024 + 4096);  \
    gload16(gb, (char*)Bs[buf_] + wave * 1024);                          \
    gload16(gb + (size_t)64 * K, (char*)Bs[buf_] + wave * 1024 + 4096);  \
  }

  const int nk = K >> 5;  // >= 24 for all our shapes
  GSTAGE(0, 0);
  GSTAGE(1, 1);
  GSTAGE(2, 2);
  GSTAGE(3, 3);

  int rd = 0;
  for (int kt = 0; kt < nk; ++kt) {
    const int rem = nk - kt;
    if (rem >= 4)
      asm volatile("s_waitcnt vmcnt(12)" ::: "memory");
    else if (rem == 3)
      asm volatile("s_waitcnt vmcnt(8)" ::: "memory");
    else if (rem == 2)
      asm volatile("s_waitcnt vmcnt(4)" ::: "memory");
    else
      asm volatile("s_waitcnt vmcnt(0)" ::: "memory");
    __builtin_amdgcn_s_barrier();

    short8 af[4], bf[4];
#pragma unroll
    for (int m = 0; m < 4; ++m)
      af[m] = *(const short8*)(As[rd] + (wm * 64 + m * 16 + r15) * 32 + g * 8);
#pragma unroll
    for (int n = 0; n < 4; ++n)
      bf[n] = *(const short8*)(Bs[rd] + (wn * 64 + n * 16 + r15) * 32 + g * 8);

    if (kt + 4 < nk) {
      const int wr = (rd == 0) ? 4 : rd - 1;  // == (kt+4)%5
      GSTAGE(kt + 4, wr);
    }

    asm volatile("s_waitcnt lgkmcnt(0)" ::: "memory");
    __builtin_amdgcn_sched_barrier(0);
    __builtin_amdgcn_s_setprio(1);
#pragma unroll
    for (int m = 0; m < 4; ++m)
#pragma unroll
      for (int n = 0; n < 4; ++n)
        acc[m][n] = __builtin_amdgcn_mfma_f32_16x16x32_bf16(af[m], bf[n], acc[m][n], 0, 0, 0);
    __builtin_amdgcn_s_setprio(0);
    rd = (rd == 4) ? 0 : rd + 1;
  }
#undef GSTAGE

#pragma unroll
  for (int m = 0; m < 4; ++m) {
#pragma unroll
    for (int n = 0; n < 4; ++n) {
#pragma unroll
      for (int r = 0; r < 4; ++r) {
        const int row = bm * 128 + wm * 64 + m * 16 + g * 4 + r;
        const int col = bn * 128 + wn * 64 + n * 16 + r15;
        float v = acc[m][n][r] + bias[col];
        if (GELU) v = 0.5f * v * (1.f + erff(v * 0.70710678118654752f));
        if (RES) v += res[(size_t)row * Nn + col];
        if (OUTF) outF[(size_t)row * Nn + col] = v;
        if (OUTB) outB[(size_t)row * Nn + col] = f2bf(v);
      }
    }
  }
}

// ---------------- fused biased attention (32KB LDS, full residency) ----------
// K double-buffered (global_load_lds), V single-buffered (reg-staged,
// written at top barrier where prev PV is provably complete), Ps per-wave.
// Second barrier per tile is lgkm-only (global prefetch stays in flight).
// grid: (N/64, B*H) = 768 blocks = 3/CU resident; block: 256.
__global__ __launch_bounds__(256) void attn_kernel(const unsigned short* __restrict__ qkv,
                                                   const float* __restrict__ pbias,
                                                   unsigned short* __restrict__ o) {
  __shared__ unsigned short Ks[2][64 * 64];
  __shared__ unsigned short Vt[64 * 64];
  __shared__ unsigned short Ps[4][16 * 64];
  const int t = threadIdx.x, lane = t & 63, wave = t >> 6;
  const int bh = blockIdx.y;
  const int b = bh / H_, h = bh % H_;
  const int q0 = blockIdx.x * 64;
  const int r15 = lane & 15, g = lane >> 4;
  const int qrow = q0 + wave * 16;
  const float LOG2E = 1.44269504088896f;
  const float QS = 0.125f * 1.44269504088896f;  // SCALE * log2(e)
  const int NT = N_ / 64;

  short8 aq[2];
  {
    const unsigned short* qp =
        qkv + (size_t)(b * N_ + qrow + r15) * (3 * C_) + h * D_ + g * 8;
    const ushort8 r0 = *(const ushort8*)qp;
    const ushort8 r1 = *(const ushort8*)(qp + 32);
#pragma unroll
    for (int j = 0; j < 8; ++j) {
      aq[0][j] = (short)f2bf(bf2f(r0[j]) * QS);
      aq[1][j] = (short)f2bf(bf2f(r1[j]) * QS);
    }
  }

  f32x4 oacc[4];
#pragma unroll
  for (int n = 0; n < 4; ++n) oacc[n] = (f32x4){0.f, 0.f, 0.f, 0.f};
  float m_run[4], l_run[4];
#pragma unroll
  for (int r = 0; r < 4; ++r) { m_run[r] = -1e30f; l_run[r] = 0.f; }

  const unsigned short* kbase = qkv + (size_t)b * N_ * (3 * C_) + C_ + h * D_;
  const unsigned short* vbase = qkv + (size_t)b * N_ * (3 * C_) + 2 * C_ + h * D_;
  const float* bb = pbias + (size_t)b * N_ * N_;

  const int krow = t >> 3;
  const int kchunk = (t & 7) ^ (krow & 7);
  const int vp = t & 31;
  const int vq = t >> 5;
  const int vkey = vp * 2, vd0 = vq * 8;

#define KSTAGE(kb_, nb_)                                                       \
  {                                                                            \
    const unsigned short* kg =                                                 \
        kbase + (size_t)((kb_)*64 + krow) * (3 * C_) + kchunk * 8;             \
    gload16(kg, (char*)Ks[nb_] + wave * 1024);                                 \
    gload16(kg + (size_t)32 * (3 * C_), (char*)Ks[nb_] + wave * 1024 + 4096);  \
  }

#define VWRITE(va_, vb_)                                                             \
  {                                                                                  \
    char* vdst = (char*)Vt;                                                          \
    _Pragma("unroll") for (int jj = 0; jj < 8; ++jj) {                               \
      const int d = vd0 + jj;                                                        \
      const unsigned int pack =                                                      \
          (unsigned int)(va_)[jj] | ((unsigned int)(vb_)[jj] << 16);                 \
      *(unsigned int*)(vdst + d * 128 + (((vp >> 2) ^ (d & 7)) << 4) +               \
                       (vp & 3) * 4) = pack;                                         \
    }                                                                                \
  }

  // Prologue: K(0) -> LDS (async), V(0)/bias(0) -> regs.
  KSTAGE(0, 0);
  ushort8 va, vb2;
  {
    const unsigned short* vg = vbase + (size_t)vkey * (3 * C_) + vd0;
    va = *(const ushort8*)vg;
    vb2 = *(const ushort8*)(vg + 3 * C_);
  }
  float bcur[4][4], bnext[4][4];
#pragma unroll
  for (int n = 0; n < 4; ++n)
#pragma unroll
    for (int r = 0; r < 4; ++r)
      bcur[n][r] = bb[(size_t)(qrow + g * 4 + r) * N_ + n * 16 + r15];

  for (int kb = 0; kb < NT; ++kb) {
    const int cur = kb & 1;
    __syncthreads();  // K[kb] staged & visible; all waves' PV[kb-1] complete

    VWRITE(va, vb2);  // Vt <- V tile kb (single buffer, safe after barrier)

    const bool more = (kb + 1 < NT);
    if (more) {
      KSTAGE(kb + 1, cur ^ 1);
      const unsigned short* vg =
          vbase + (size_t)((kb + 1) * 64 + vkey) * (3 * C_) + vd0;
      va = *(const ushort8*)vg;
      vb2 = *(const ushort8*)(vg + 3 * C_);
#pragma unroll
      for (int n = 0; n < 4; ++n)
#pragma unroll
        for (int r = 0; r < 4; ++r)
          bnext[n][r] =
              bb[(size_t)(qrow + g * 4 + r) * N_ + (kb + 1) * 64 + n * 16 + r15];
    }

    // S = Q K^T (16 x 64 per wave), log2-scaled domain
    const unsigned short* Ksc = Ks[cur];
    f32x4 sacc[4];
#pragma unroll
    for (int n = 0; n < 4; ++n) sacc[n] = (f32x4){0.f, 0.f, 0.f, 0.f};
    __builtin_amdgcn_s_setprio(1);
#pragma unroll
    for (int kk = 0; kk < 2; ++kk) {
#pragma unroll
      for (int n = 0; n < 4; ++n) {
        short8 bk = *(const short8*)(Ksc + (n * 16 + r15) * 64 +
                                     (((kk * 4 + g) ^ (r15 & 7)) << 3));
        sacc[n] = __builtin_amdgcn_mfma_f32_16x16x32_bf16(aq[kk], bk, sacc[n], 0, 0, 0);
      }
    }
    __builtin_amdgcn_s_setprio(0);

    // online softmax (log2 domain, defer-max)
    float p[4][4], tm[4];
#pragma unroll
    for (int r = 0; r < 4; ++r) tm[r] = -3e38f;
#pragma unroll
    for (int n = 0; n < 4; ++n)
#pragma unroll
      for (int r = 0; r < 4; ++r) {
        const float s = fmaf(bcur[n][r], LOG2E, sacc[n][r]);
        p[n][r] = s;
        tm[r] = fmaxf(tm[r], s);
      }
#pragma unroll
    for (int r = 0; r < 4; ++r) {
      tm[r] = fmaxf(tm[r], __shfl_xor(tm[r], 1));
      tm[r] = fmaxf(tm[r], __shfl_xor(tm[r], 2));
      tm[r] = fmaxf(tm[r], __shfl_xor(tm[r], 4));
      tm[r] = fmaxf(tm[r], __shfl_xor(tm[r], 8));
    }
    int need = 0;
#pragma unroll
    for (int r = 0; r < 4; ++r) need |= (tm[r] > m_run[r] + 8.0f);
    if (__any(need)) {
#pragma unroll
      for (int r = 0; r < 4; ++r) {
        const float mn = fmaxf(m_run[r], tm[r]);
        const float corr = ex2(m_run[r] - mn);
        m_run[r] = mn;
        l_run[r] *= corr;
#pragma unroll
        for (int n = 0; n < 4; ++n) oacc[n][r] *= corr;
      }
    }
    float rs[4] = {0.f, 0.f, 0.f, 0.f};
#pragma unroll
    for (int n = 0; n < 4; ++n)
#pragma unroll
      for (int r = 0; r < 4; ++r) {
        p[n][r] = ex2(p[n][r] - m_run[r]);
        rs[r] += p[n][r];
      }
#pragma unroll
    for (int r = 0; r < 4; ++r) {
      rs[r] += __shfl_xor(rs[r], 1);
      rs[r] += __shfl_xor(rs[r], 2);
      rs[r] += __shfl_xor(rs[r], 4);
      rs[r] += __shfl_xor(rs[r], 8);
      l_run[r] += rs[r];
    }

    // P -> per-wave LDS (swizzled)
    unsigned short* Psw = Ps[wave];
#pragma unroll
    for (int n = 0; n < 4; ++n)
#pragma unroll
      for (int r = 0; r < 4; ++r) {
        const int row = g * 4 + r, col = n * 16 + r15;
        Psw[row * 64 + (((col >> 3) ^ (row & 7)) << 3) + (col & 7)] = f2bf(p[n][r]);
      }

    // lgkm-only barrier: all waves' VWRITE (and own Ps writes) visible;
    // global prefetch (K/V/bias for kb+1) stays in flight.
    asm volatile("s_waitcnt lgkmcnt(0)" ::: "memory");
    __builtin_amdgcn_s_barrier();
    __builtin_amdgcn_sched_barrier(0);

    // O += P V
    __builtin_amdgcn_s_setprio(1);
#pragma unroll
    for (int kk = 0; kk < 2; ++kk) {
      short8 ap = *(const short8*)(Psw + r15 * 64 + (((kk * 4 + g) ^ (r15 & 7)) << 3));
#pragma unroll
      for (int n = 0; n < 4; ++n) {
        short8 bv = *(const short8*)(Vt + (n * 16 + r15) * 64 +
                                     (((kk * 4 + g) ^ (r15 & 7)) << 3));
        oacc[n] = __builtin_amdgcn_mfma_f32_16x16x32_bf16(ap, bv, oacc[n], 0, 0, 0);
      }
    }
    __builtin_amdgcn_s_setprio(0);

    if (more) {
#pragma unroll
      for (int n = 0; n < 4; ++n)
#pragma unroll
        for (int r = 0; r < 4; ++r) bcur[n][r] = bnext[n][r];
    }
  }
#undef KSTAGE
#undef VWRITE

  // normalize and store o (bf16); rcp instead of 16 divides
  float rl[4];
#pragma unroll
  for (int r = 0; r < 4; ++r) rl[r] = frcp(l_run[r]);
#pragma unroll
  for (int n = 0; n < 4; ++n) {
#pragma unroll
    for (int r = 0; r < 4; ++r) {
      const int row = qrow + g * 4 + r;
      const float v = oacc[n][r] * rl[r];
      o[(size_t)(b * N_ + row) * C_ + h * D_ + n * 16 + r15] = f2bf(v);
    }
  }
}

// ---------------- launcher ----------------
extern "C" void kernel_launch(void* const* d_in, const int* in_sizes, int n_in,
                              void* d_out, int out_size, void* d_ws, size_t ws_size,
                              hipStream_t stream) {
  const float* x      = (const float*)d_in[0];
  const float* pbias  = (const float*)d_in[1];
  const float* qkv_w  = (const float*)d_in[2];
  const float* qkv_b  = (const float*)d_in[3];
  const float* proj_w = (const float*)d_in[4];
  const float* proj_b = (const float*)d_in[5];
  const float* n1_w   = (const float*)d_in[6];
  const float* n1_b   = (const float*)d_in[7];
  const float* n2_w   = (const float*)d_in[8];
  const float* n2_b   = (const float*)d_in[9];
  const float* fc1_w  = (const float*)d_in[10];
  const float* fc1_b  = (const float*)d_in[11];
  const float* fc2_w  = (const float*)d_in[12];
  const float* fc2_b  = (const float*)d_in[13];
  float* out = (float*)d_out;

  char* ws = (char*)d_ws;
  unsigned short* wt_qkv  = (unsigned short*)(ws + 0);          // 2304x768
  unsigned short* wt_proj = (unsigned short*)(ws + 3538944);    // 768x768
  unsigned short* wt_fc1  = (unsigned short*)(ws + 4718592);    // 3072x768
  unsigned short* wt_fc2  = (unsigned short*)(ws + 9437184);    // 768x3072
  float*          x2      = (float*)(ws + 14155776);            // 4096x768 fp32
  unsigned short* h1      = (unsigned short*)(ws + 26738688);   // 4096x768 bf16
  unsigned short* qkvb    = (unsigned short*)(ws + 33030144);   // 4096x2304 bf16

  wconv_all<<<1728 + 576 + 2304 + 2304, 256, 0, stream>>>(
      qkv_w, proj_w, fc1_w, fc2_w, wt_qkv, wt_proj, wt_fc1, wt_fc2);

  ln_kernel<<<M_, 256, 0, stream>>>(x, n1_w, n1_b, h1);
  gemm_bt<false, false, false, true><<<dim3(32, 18), 256, 0, stream>>>(
      h1, wt_qkv, qkv_b, nullptr, nullptr, qkvb, M_, 3 * C_, C_);
  attn_kernel<<<dim3(N_ / 64, B_ * H_), 256, 0, stream>>>(qkvb, pbias, h1);
  gemm_bt<false, true, true, false><<<dim3(32, 6), 256, 0, stream>>>(
      h1, wt_proj, proj_b, x, x2, nullptr, M_, C_, C_);
  ln_kernel<<<M_, 256, 0, stream>>>(x2, n2_w, n2_b, h1);
  gemm_bt<true, false, false, true><<<dim3(32, 24), 256, 0, stream>>>(
      h1, wt_fc1, fc1_b, nullptr, nullptr, qkvb, M_, HID_, C_);
  gemm_bt<false, true, true, false><<<dim3(32, 6), 256, 0, stream>>>(
      qkvb, wt_fc2, fc2_b, x2, out, nullptr, M_, C_, HID_);
}